// Round 4
// baseline (390.077 us; speedup 1.0000x reference)
//
#include <hip/hip_runtime.h>
#include <math.h>

#define PI_F 3.14159265358979323846f
#define NPIX 262144   // 512*512

typedef __attribute__((ext_vector_type(8))) short sh8;
typedef __attribute__((ext_vector_type(4))) float fx4;
typedef __attribute__((ext_vector_type(4))) unsigned short ush4;

__device__ __forceinline__ unsigned short f2bf(float v) {
    unsigned u = __float_as_uint(v);
    return (unsigned short)((u + 0x7FFFu + ((u >> 16) & 1)) >> 16);
}
__device__ __forceinline__ float bf2f(unsigned short h) {
    return __uint_as_float((unsigned)h << 16);
}

__device__ __forceinline__ int refl512(int t) {
    if (t < 0) t = -t;
    if (t > 511) t = 1022 - t;
    return t;
}

// ---------------------------------------------------------------- dark channel (fused min-c + row-min)
__global__ __launch_bounds__(256) void k_mrow(const float* __restrict__ x, float* __restrict__ tmp,
                                              int* __restrict__ gmax) {
    __shared__ float row[512];
    int i = blockIdx.x, tid = threadIdx.x;
    if (i == 0 && tid == 0) gmax[0] = 0;
    #pragma unroll
    for (int h = 0; h < 2; h++) {
        int j = tid + h * 256;
        int p = (i << 9) + j;
        float m = fmaxf(x[p], fmaxf(x[p + NPIX], x[p + 2 * NPIX]));
        row[j] = 1.0f - m;
    }
    __syncthreads();
    #pragma unroll
    for (int h = 0; h < 2; h++) {
        int j = tid + h * 256;
        float m = 1e30f;
        #pragma unroll
        for (int d = -7; d <= 7; d++) m = fminf(m, row[refl512(j + d)]);
        tmp[(i << 9) + j] = m;
    }
}

__global__ __launch_bounds__(256) void k_mincol_max(const float* __restrict__ tmp, float* __restrict__ dark,
                                                    int* __restrict__ gmax) {
    int p = blockIdx.x * 256 + threadIdx.x;
    int i = p >> 9, j = p & 511;
    float m = 1e30f;
    #pragma unroll
    for (int d = -7; d <= 7; d++) m = fminf(m, tmp[(refl512(i + d) << 9) + j]);
    dark[p] = m;
    __shared__ float red[256];
    int tid = threadIdx.x;
    red[tid] = m;
    __syncthreads();
    for (int s = 128; s > 0; s >>= 1) {
        if (tid < s) red[tid] = fmaxf(red[tid], red[tid + s]);
        __syncthreads();
    }
    if (tid == 0) atomicMax(gmax, __float_as_int(red[0]));
}

// ---------------------------------------------------------------- prep helpers (device)
__device__ __forceinline__ void prep_one(const float* __restrict__ w, unsigned short* __restrict__ h,
                                         unsigned short* __restrict__ l, int N, int K, int cshift, int idx) {
    if (idx >= N * K) return;
    int n = idx / K, kord = idx - n * K;
    int ksrc = kord;
    if (cshift) {
        int dydx = kord >> cshift, c = kord & ((1 << cshift) - 1);
        ksrc = c * 4 + dydx;
    }
    float v = w[n * K + ksrc];
    unsigned short hb = f2bf(v);
    h[idx] = hb;
    if (l) l[idx] = f2bf(v - bf2f(hb));
}

// ---------------------------------------------------------------- split prep kernels
__global__ __launch_bounds__(256) void k_prepw(
    const float* __restrict__ w_d2, unsigned short* __restrict__ d2h, unsigned short* __restrict__ d2l,
    const float* __restrict__ w_a1, unsigned short* __restrict__ a1h, unsigned short* __restrict__ a1l,
    const float* __restrict__ w_a2, unsigned short* __restrict__ a2h, unsigned short* __restrict__ a2l,
    const float* __restrict__ w_s1, unsigned short* __restrict__ s1h) {
    int b = blockIdx.x, tid = threadIdx.x;
    if (b < 512)       prep_one(w_d2, d2h, d2l, 256, 512, 7, b * 256 + tid);
    else if (b < 768)  prep_one(w_a1, a1h, a1l, 256, 256, 0, (b - 512) * 256 + tid);
    else if (b < 1024) prep_one(w_a2, a2h, a2l, 256, 256, 0, (b - 768) * 256 + tid);
    else               prep_one(w_s1, s1h, nullptr, 256, 256, 0, (b - 1024) * 256 + tid);
}

__global__ __launch_bounds__(256) void k_prepf(
    unsigned short* __restrict__ BfH, unsigned short* __restrict__ BfL,
    unsigned short* __restrict__ BfcH, unsigned short* __restrict__ BfcL,
    unsigned short* __restrict__ BicH, unsigned short* __restrict__ BicL,
    unsigned short* __restrict__ BirH, unsigned short* __restrict__ BirL,
    float* __restrict__ zbias) {
    int idx = blockIdx.x * 256 + threadIdx.x;
    if (idx < 256) zbias[idx] = 0.f;
    const float w0 = 2.f * PI_F / 128.f;
    float v;
    unsigned short *H, *L;
    int off;
    if (idx < 32768) {                     // Bf [256][128]
        int n = idx >> 7, k = idx & 127;
        int t = n & 127, r = (t * k) & 127;
        float s_, c_; sincosf(w0 * r, &s_, &c_);
        v = (n < 128) ? c_ : -s_;
        H = BfH; L = BfL; off = idx;
    } else if (idx < 98304) {              // Bfc [256][256]
        int i = idx - 32768;
        int n = i >> 8, j = i & 255;
        int t = n & 127, r = (t * (j & 127)) & 127;
        float s_, c_; sincosf(w0 * r, &s_, &c_);
        v = (n < 128) ? ((j < 128) ? c_ : s_) : ((j < 128) ? -s_ : c_);
        H = BfcH; L = BfcL; off = i;
    } else if (idx < 163840) {             // Bic [256][256]
        int i = idx - 98304;
        int n = i >> 8, j = i & 255;
        int t = n & 127, r = (t * (j & 127)) & 127;
        float s_, c_; sincosf(w0 * r, &s_, &c_);
        v = ((n < 128) ? ((j < 128) ? c_ : -s_) : ((j < 128) ? s_ : c_)) * (1.f / 128.f);
        H = BicH; L = BicL; off = i;
    } else if (idx < 184320) {             // Bir [128][160]
        int i = idx - 163840;
        int col = i / 160, j = i - col * 160;
        if (j == 0) v = 1.f / 128.f;
        else if (j < 64)  { int r = (j * col) & 127; float s_, c_; sincosf(w0 * r, &s_, &c_); v = 2.f * c_ / 128.f; }
        else if (j == 64) v = (col & 1) ? -1.f / 128.f : 1.f / 128.f;
        else if (j >= 66 && j <= 128) { int k = j - 65; int r = (k * col) & 127; float s_, c_; sincosf(w0 * r, &s_, &c_); v = -2.f * s_ / 128.f; }
        else v = 0.f;
        H = BirH; L = BirL; off = i;
    } else return;
    unsigned short hb = f2bf(v);
    H[off] = hb;
    L[off] = f2bf(v - bf2f(hb));
}

__global__ __launch_bounds__(256) void k_prepu(const float* __restrict__ w_u3, const float* __restrict__ w_u4,
                                               float* __restrict__ Uf) {
    int idx = blockIdx.x * 256 + threadIdx.x;
    int n = idx >> 8, j = idx & 255;
    float s = 0.f;
    #pragma unroll 16
    for (int o = 0; o < 128; o++) s += w_u4[n * 128 + o] * w_u3[o * 256 + j];
    Uf[idx] = s;
}

__global__ __launch_bounds__(256) void k_prepc(
    const float* __restrict__ w_e1, const float* __restrict__ b_e1,
    const float* __restrict__ w_e2, const float* __restrict__ b_e2,
    const float* __restrict__ w_d1, const float* __restrict__ b_d1,
    unsigned short* __restrict__ d1ch, float* __restrict__ b1c,
    const float* __restrict__ w2, const float* __restrict__ b2,
    const float* __restrict__ w3, const float* __restrict__ b3,
    const float* __restrict__ wu2, const float* __restrict__ bu2,
    const float* __restrict__ wu1, const float* __restrict__ bu1,
    float* __restrict__ Wc, float* __restrict__ bc,
    float* __restrict__ W21c, float* __restrict__ b21c) {
    int b = blockIdx.x, tid = threadIdx.x;
    if (b < 16) {
        __shared__ float E[192];
        if (tid < 192) {
            int o = tid / 3, ci = tid - o * 3;
            float s = 0.f;
            #pragma unroll
            for (int r = 0; r < 8; r++) s += w_e2[o * 8 + r] * w_e1[r * 3 + ci];
            E[tid] = s;
        }
        __syncthreads();
        int idx = b * 256 + tid;           // < 4096
        int n = idx >> 5, k = idx & 31;
        float s = 0.f;
        if (k < 12) {
            int dydx = k / 3, ci = k - dydx * 3;
            #pragma unroll 16
            for (int o = 0; o < 64; o++) s += w_d1[n * 256 + o * 4 + dydx] * E[o * 3 + ci];
        }
        d1ch[idx] = f2bf(s);
    } else if (b == 16) {
        __shared__ float f[64];
        if (tid < 64) {
            int o = tid;
            float s = b_e2[o];
            #pragma unroll
            for (int r = 0; r < 8; r++) s += w_e2[o * 8 + r] * b_e1[r];
            f[o] = s;
        }
        __syncthreads();
        if (tid < 128) {
            float s = b_d1[tid];
            #pragma unroll 8
            for (int o = 0; o < 64; o++) {
                float fo = f[o];
                #pragma unroll
                for (int dydx = 0; dydx < 4; dydx++) s += w_d1[tid * 256 + o * 4 + dydx] * fo;
            }
            b1c[tid] = s;
        }
    } else {
        __shared__ float sWc[384], sW2c[384];
        if (tid < 128) {
            int j = tid;
            for (int r = 0; r < 3; r++) {
                float s = 0.f;
                #pragma unroll 16
                for (int o = 0; o < 64; o++) s += w3[r * 64 + o] * w2[o * 128 + j];
                sWc[r * 128 + j] = s;
                Wc[r * 128 + j] = s;
            }
            if (j < 3) {
                float s = b3[j];
                #pragma unroll 16
                for (int o = 0; o < 64; o++) s += w3[j * 64 + o] * b2[o];
                bc[j] = s;
            }
        }
        __syncthreads();
        if (tid < 128) {
            int j = tid;
            for (int r = 0; r < 3; r++) {
                float s = 0.f;
                #pragma unroll 16
                for (int o = 0; o < 64; o++) s += sWc[r * 128 + o] * wu2[o * 128 + j];
                sW2c[r * 128 + j] = s;
            }
        }
        __syncthreads();
        if (tid < 256) {
            int j = tid;
            for (int r = 0; r < 3; r++) {
                float s = 0.f;
                #pragma unroll 16
                for (int o = 0; o < 128; o++) s += sW2c[r * 128 + o] * wu1[o * 256 + j];
                W21c[r * 256 + j] = s;
            }
        }
        if (tid < 3) {
            float s = 0.f;
            #pragma unroll 16
            for (int o = 0; o < 128; o++) s += sW2c[tid * 128 + o] * bu1[o];
            #pragma unroll 16
            for (int o = 0; o < 64; o++)  s += sWc[tid * 128 + o] * bu2[o];
            b21c[tid] = s;
        }
    }
}

__global__ __launch_bounds__(64) void k_prepb43(const float* __restrict__ w_u4, const float* __restrict__ b_u3,
                                                const float* __restrict__ b_u4, float* __restrict__ b43) {
    int n = threadIdx.x;
    float s = b_u4[n];
    #pragma unroll 16
    for (int o = 0; o < 128; o++) s += w_u4[n * 128 + o] * b_u3[o];
    b43[n] = s;
}

// ---------------------------------------------------------------- Wg = (u4·u3)·w_sp2 compose, b_g fold
__global__ __launch_bounds__(256) void k_prep2(const float* __restrict__ Uf, const float* __restrict__ wsp2,
                                               const float* __restrict__ bsp2, const float* __restrict__ b43,
                                               unsigned short* __restrict__ Wg, float* __restrict__ bgc) {
    __shared__ float u[256], red[256];
    int n = blockIdx.x, tid = threadIdx.x;
    u[tid] = Uf[n * 256 + tid];
    __syncthreads();
    float s = 0.f;
    #pragma unroll 16
    for (int o = 0; o < 256; o++) s += u[o] * wsp2[o * 256 + tid];
    Wg[n * 256 + tid] = f2bf(s);
    red[tid] = u[tid] * bsp2[tid];
    __syncthreads();
    for (int st = 128; st > 0; st >>= 1) {
        if (tid < st) red[tid] += red[tid + st];
        __syncthreads();
    }
    if (tid == 0) bgc[n] = b43[n] + red[0];
}

// ---------------------------------------------------------------- channels-first MFMA GEMM
template<int AMODE, int SPLIT, int LRELU, int TSTORE, int ABF16, int CBF16>
__global__ __launch_bounds__(256) void k_mmcf(const void* __restrict__ Asrc_,
                                              const unsigned short* __restrict__ Bh,
                                              const unsigned short* __restrict__ Bl,
                                              const float* __restrict__ bias, void* __restrict__ C_,
                                              int M, int N, int K, int cshift, int wshift, int srcW,
                                              int gy) {
    const float* Af = (const float*)Asrc_;
    const unsigned short* A16 = (const unsigned short*)Asrc_;
    float* Cf = (float*)C_;
    unsigned short* C16 = (unsigned short*)C_;
    __shared__ unsigned short AhS[128 * 40];
    __shared__ unsigned short BhS[64 * 40];
    __shared__ unsigned short AlS[SPLIT ? 128 * 40 : 8];
    __shared__ unsigned short BlS[SPLIT ? 64 * 40 : 8];
    int tid = threadIdx.x;
    int nwg = (int)gridDim.x;
    int bid = blockIdx.x;
    int qq = nwg >> 3, rr = nwg & 7;
    int xcd = bid & 7, ixw = bid >> 3;
    int work = (xcd < rr) ? (xcd * (qq + 1) + ixw) : (rr * (qq + 1) + (xcd - rr) * qq + ixw);
    int bx = work / gy;
    int by = work - bx * gy;
    int m0 = bx * 128;
    int n0 = by * 64;
    int wave = tid >> 6, lane = tid & 63;
    int wm = (wave >> 1) * 64, wn = (wave & 1) * 32;
    int l15 = lane & 15, quad = lane >> 4;
    int lk = quad * 8, lk4 = quad * 4;
    fx4 acc[4][2];
    #pragma unroll
    for (int a = 0; a < 4; a++)
        #pragma unroll
        for (int b = 0; b < 2; b++)
            acc[a][b] = (fx4){0.f, 0.f, 0.f, 0.f};

    int mm = tid & 127;
    int kpb = tid >> 7;
    int gm = m0 + mm;
    int oj = 0, oi = 0, cA = 0, kfA = 0, tauA = 0;
    size_t abase = 0;
    if (AMODE == 1) { oj = gm & ((1 << wshift) - 1); oi = gm >> wshift; }
    if (AMODE == 2) { oj = gm & 255; oi = gm >> 8; }
    if (AMODE == 3) abase = (size_t)gm * K;
    if (AMODE == 7) { cA = gm / 65; kfA = gm - cA * 65; }
    if (AMODE == 8) { cA = gm >> 7; tauA = gm & 127; }
    if (AMODE == 9) { cA = gm / 65; kfA = gm - cA * 65; }

    for (int kb = 0; kb < K; kb += 32) {
        if (AMODE == 3 && ABF16 && !SPLIT) {
            #pragma unroll
            for (int half = 0; half < 2; half++) {
                sh8 hv = *(const sh8*)(const void*)&A16[abase + kb + kpb * 16 + half * 8];
                *(sh8*)(void*)&AhS[mm * 40 + (kpb * 2 + half) * 8] = hv;
            }
        } else {
            #pragma unroll
            for (int half = 0; half < 2; half++) {
                sh8 hv, lv;
                #pragma unroll
                for (int tt = 0; tt < 4; tt++) {
                    int kp = kpb * 8 + half * 4 + tt;
                    int k0 = kb + kp * 2;
                    unsigned short h0, h1;
                    if (ABF16) {
                        size_t ad0, ad1;
                        if (AMODE == 0) {
                            ad0 = (size_t)k0 * M + gm;
                            ad1 = ad0 + M;
                        } else if (AMODE == 1) {
                            int c = k0 & ((1 << cshift) - 1);
                            int dydx = k0 >> cshift;
                            int dy = dydx >> 1, dx = dydx & 1;
                            size_t pix = (size_t)(2 * oi + dy) * srcW + (2 * oj + dx);
                            size_t plane = (size_t)srcW * srcW;
                            ad0 = (size_t)c * plane + pix;
                            ad1 = ad0 + plane;
                        } else if (AMODE == 3) {
                            ad0 = abase + k0;
                            ad1 = ad0 + 1;
                        } else if (AMODE == 7) {
                            int t0 = k0 & 127, hf = k0 >> 7;
                            ad0 = (size_t)(cA * 128 + t0) * 256 + hf * 128 + kfA;
                            ad1 = ad0 + 256;
                        } else {               // AMODE 8
                            int j0 = k0, j1 = k0 + 1;
                            int kf0 = (j0 < 65) ? j0 : ((j0 < 130) ? j0 - 65 : 0);
                            int hf0 = (j0 >= 65 && j0 < 130) ? 1 : 0;
                            int kf1 = (j1 < 65) ? j1 : ((j1 < 130) ? j1 - 65 : 0);
                            int hf1 = (j1 >= 65 && j1 < 130) ? 1 : 0;
                            ad0 = (size_t)(cA * 65 + kf0) * 256 + hf0 * 128 + tauA;
                            ad1 = (size_t)(cA * 65 + kf1) * 256 + hf1 * 128 + tauA;
                        }
                        h0 = A16[ad0];
                        h1 = A16[ad1];
                    } else {
                        float a0, a1;
                        if (AMODE == 2) {
                            if (k0 < 12) {
                                int d0 = k0 / 3, c0 = k0 - d0 * 3;
                                int k1 = k0 + 1;
                                int d1x = k1 / 3, c1 = k1 - d1x * 3;
                                a0 = Af[(size_t)c0 * NPIX + (size_t)(2 * oi + (d0 >> 1)) * 512 + 2 * oj + (d0 & 1)];
                                a1 = Af[(size_t)c1 * NPIX + (size_t)(2 * oi + (d1x >> 1)) * 512 + 2 * oj + (d1x & 1)];
                            } else { a0 = 0.f; a1 = 0.f; }
                        } else if (AMODE == 9) {
                            size_t ad = (size_t)cA * 16640 + (size_t)k0 * 65 + kfA;
                            float re0 = Af[ad], im0 = Af[ad + 2129920];
                            float re1 = Af[ad + 65], im1 = Af[ad + 65 + 2129920];
                            a0 = sqrtf(re0 * re0 + im0 * im0);
                            a1 = sqrtf(re1 * re1 + im1 * im1);
                        } else {
                            size_t ad0 = (size_t)k0 * M + gm;
                            a0 = Af[ad0];
                            a1 = Af[ad0 + M];
                        }
                        h0 = f2bf(a0);
                        h1 = f2bf(a1);
                        if (SPLIT) {
                            lv[tt * 2] = (short)f2bf(a0 - bf2f(h0));
                            lv[tt * 2 + 1] = (short)f2bf(a1 - bf2f(h1));
                        }
                    }
                    hv[tt * 2] = (short)h0;
                    hv[tt * 2 + 1] = (short)h1;
                }
                int coff = (kpb * 2 + half) * 8;
                *(sh8*)(void*)&AhS[mm * 40 + coff] = hv;
                if (SPLIT) *(sh8*)(void*)&AlS[mm * 40 + coff] = lv;
            }
        }
        {
            int n = tid >> 2, seg = tid & 3;
            size_t gb = (size_t)(n0 + n) * K + kb + seg * 8;
            *(sh8*)(void*)&BhS[n * 40 + seg * 8] = *(const sh8*)(const void*)&Bh[gb];
            if (SPLIT) *(sh8*)(void*)&BlS[n * 40 + seg * 8] = *(const sh8*)(const void*)&Bl[gb];
        }
        __syncthreads();
        sh8 af[4], bf[2], afl[4], bfl[2];
        #pragma unroll
        for (int mt = 0; mt < 4; mt++) {
            af[mt] = *(const sh8*)(const void*)&AhS[(wm + mt * 16 + l15) * 40 + lk];
            if (SPLIT) afl[mt] = *(const sh8*)(const void*)&AlS[(wm + mt * 16 + l15) * 40 + lk];
        }
        #pragma unroll
        for (int nt = 0; nt < 2; nt++) {
            bf[nt] = *(const sh8*)(const void*)&BhS[(wn + nt * 16 + l15) * 40 + lk];
            if (SPLIT) bfl[nt] = *(const sh8*)(const void*)&BlS[(wn + nt * 16 + l15) * 40 + lk];
        }
        #pragma unroll
        for (int mt = 0; mt < 4; mt++)
            #pragma unroll
            for (int nt = 0; nt < 2; nt++) {
                acc[mt][nt] = __builtin_amdgcn_mfma_f32_16x16x32_bf16(af[mt], bf[nt], acc[mt][nt], 0, 0, 0);
                if (SPLIT) {
                    acc[mt][nt] = __builtin_amdgcn_mfma_f32_16x16x32_bf16(af[mt], bfl[nt], acc[mt][nt], 0, 0, 0);
                    acc[mt][nt] = __builtin_amdgcn_mfma_f32_16x16x32_bf16(afl[mt], bf[nt], acc[mt][nt], 0, 0, 0);
                }
            }
        __syncthreads();
    }
    #pragma unroll
    for (int nt = 0; nt < 2; nt++) {
        int n = n0 + wn + nt * 16 + l15;
        float bs = bias[n];
        #pragma unroll
        for (int mt = 0; mt < 4; mt++) {
            int mbase = m0 + wm + mt * 16 + lk4;
            if (TSTORE) {
                #pragma unroll
                for (int r = 0; r < 4; r++) {
                    float q = acc[mt][nt][r] + bs;
                    if (LRELU) q = (q < 0.f) ? 0.1f * q : q;
                    if (CBF16) C16[(size_t)(mbase + r) * N + n] = f2bf(q);
                    else       Cf[(size_t)(mbase + r) * N + n] = q;
                }
            } else if (CBF16) {
                ush4 v;
                #pragma unroll
                for (int r = 0; r < 4; r++) {
                    float q = acc[mt][nt][r] + bs;
                    if (LRELU) q = (q < 0.f) ? 0.1f * q : q;
                    v[r] = f2bf(q);
                }
                *(ush4*)(void*)&C16[(size_t)n * M + mbase] = v;
            } else {
                float4 v;
                float* vp = (float*)&v;
                #pragma unroll
                for (int r = 0; r < 4; r++) {
                    float q = acc[mt][nt][r] + bs;
                    if (LRELU) q = (q < 0.f) ? 0.1f * q : q;
                    vp[r] = q;
                }
                *(float4*)&Cf[(size_t)n * M + mbase] = v;
            }
        }
    }
}

// ---------------------------------------------------------------- z = a*(cos a, sin a), flattened full-wave, bf16
__global__ __launch_bounds__(256) void k_zbuild(const float* __restrict__ A2, unsigned short* __restrict__ Z) {
    int idx = blockIdx.x * 256 + threadIdx.x;   // < 2129920
    int ct = idx / 65, kf = idx - ct * 65;
    int c = ct >> 7, t = ct & 127;
    float a = A2[idx];
    float s_, c_;
    sincosf(a, &s_, &c_);
    size_t m = (size_t)c * 65 + kf;
    Z[(size_t)t * 16640 + m] = f2bf(a * c_);
    Z[2129920 + (size_t)t * 16640 + m] = f2bf(a * s_);
}

// ---------------------------------------------------------------- h3s = W21c @ I2T + b21c  (3ch @128^2, K=256)
__global__ __launch_bounds__(64) void k_h3s(const float* __restrict__ I2T, const float* __restrict__ W21c,
                                            const float* __restrict__ b21c, float* __restrict__ h3s) {
    __shared__ float wa[768], bs[3];
    int tid = threadIdx.x;
    for (int i = tid; i < 768; i += 64) wa[i] = W21c[i];
    if (tid < 3) bs[tid] = b21c[tid];
    __syncthreads();
    int q = blockIdx.x * 64 + tid;
    float a0 = bs[0], a1 = bs[1], a2 = bs[2];
    #pragma unroll 4
    for (int c = 0; c < 256; c++) {
        float v = I2T[(size_t)c * 16384 + q];
        a0 += wa[c] * v;
        a1 += wa[256 + c] * v;
        a2 += wa[512 + c] * v;
    }
    h3s[q] = a0; h3s[16384 + q] = a1; h3s[32768 + q] = a2;
}

// ---------------------------------------------------------------- channels-first bilinear x2 resize
__global__ __launch_bounds__(256) void k_resize2(const float* __restrict__ src, float* __restrict__ dst,
                                                 int C, int H) {
    int W2 = 2 * H;
    size_t idx = (size_t)blockIdx.x * 256 + threadIdx.x;
    size_t plane = (size_t)W2 * W2;
    if (idx >= (size_t)C * plane) return;
    int c = (int)(idx / plane);
    int rem = (int)(idx - (size_t)c * plane);
    int i = rem / W2, j = rem - i * W2;
    int ky = i >> 1, ylo, yhi; float wyl, wyh;
    if ((i & 1) == 0) { ylo = ky - 1; yhi = ky; wyl = .25f; wyh = .75f; if (ylo < 0) { ylo = 0; wyl = 0.f; wyh = 1.f; } }
    else              { ylo = ky; yhi = ky + 1; wyl = .75f; wyh = .25f; if (yhi > H - 1) { yhi = H - 1; wyh = 0.f; wyl = 1.f; } }
    int kx = j >> 1, xlo, xhi; float wxl, wxh;
    if ((j & 1) == 0) { xlo = kx - 1; xhi = kx; wxl = .25f; wxh = .75f; if (xlo < 0) { xlo = 0; wxl = 0.f; wxh = 1.f; } }
    else              { xlo = kx; xhi = kx + 1; wxl = .75f; wxh = .25f; if (xhi > H - 1) { xhi = H - 1; wxh = 0.f; wxl = 1.f; } }
    const float* p = src + (size_t)c * H * H;
    dst[idx] = wyl * (wxl * p[(size_t)ylo * H + xlo] + wxh * p[(size_t)ylo * H + xhi]) +
               wyh * (wxl * p[(size_t)yhi * H + xlo] + wxh * p[(size_t)yhi * H + xhi]);
}

// ---------------------------------------------------------------- final fused stage @512^2
__global__ __launch_bounds__(256) void k_final(const float* __restrict__ x,
                                               const float* __restrict__ dark, const int* __restrict__ gmax,
                                               const float* __restrict__ wcf1, const float* __restrict__ bcf1,
                                               const float* __restrict__ Wc, const float* __restrict__ bc,
                                               const float* __restrict__ g4, const float* __restrict__ h3,
                                               float* __restrict__ out) {
    __shared__ float dimt[32], w1[192], b1[64], wb[192], bcs[3];
    int tid = threadIdx.x;
    if (tid < 32) dimt[tid] = powf(10000.f, (float)(2 * (tid >> 1)) / 32.f);
    if (tid < 192) w1[tid] = wcf1[tid];
    if (tid < 64) b1[tid] = bcf1[tid];
    if (tid < 192) { int r = tid / 64, c = tid - (tid / 64) * 64; wb[tid] = Wc[r * 128 + 64 + c]; }
    if (tid < 3) bcs[tid] = bc[tid];
    __syncthreads();
    int p = blockIdx.x * 256 + threadIdx.x;
    int i = p >> 9, j = p & 511;
    const float scale = 2.f * PI_F;
    float inv511 = scale / (511.f + 1e-6f);
    float xe = (float)j * inv511, ye = (float)i * inv511;
    float gm = __int_as_float(gmax[0]);
    float ze = dark[p] / (gm + 1e-6f) * scale;
    float x0 = x[p], x1 = x[p + NPIX], x2 = x[p + 2 * NPIX];

    int ky = i >> 1, ylo, yhi; float wyl, wyh;
    if ((i & 1) == 0) { ylo = ky - 1; yhi = ky; wyl = .25f; wyh = .75f; if (ylo < 0) { ylo = 0; wyl = 0.f; wyh = 1.f; } }
    else              { ylo = ky; yhi = ky + 1; wyl = .75f; wyh = .25f; if (yhi > 255) { yhi = 255; wyh = 0.f; wyl = 1.f; } }
    int kx = j >> 1, xlo, xhi; float wxl, wxh;
    if ((j & 1) == 0) { xlo = kx - 1; xhi = kx; wxl = .25f; wxh = .75f; if (xlo < 0) { xlo = 0; wxl = 0.f; wxh = 1.f; } }
    else              { xlo = kx; xhi = kx + 1; wxl = .75f; wxh = .25f; if (xhi > 255) { xhi = 255; wxh = 0.f; wxl = 1.f; } }
    int s00 = ylo * 256 + xlo, s01 = ylo * 256 + xhi, s10 = yhi * 256 + xlo, s11 = yhi * 256 + xhi;
    float w00 = wyl * wxl, w01 = wyl * wxh, w10 = wyh * wxl, w11 = wyh * wxh;

    float a0 = 0.f, a1 = 0.f, a2 = 0.f;
    #pragma unroll 1
    for (int c = 0; c < 64; c++) {
        float e = (c < 16) ? xe / dimt[c] : (c < 32) ? ye / dimt[c - 16] : ze / dimt[c - 32];
        float sn, cs;
        __sincosf(e, &sn, &cs);
        float pos = ((c & 1) == 0) ? sn : cs;
        float ape = pos + w1[c * 3] * x0 + w1[c * 3 + 1] * x1 + w1[c * 3 + 2] * x2 + b1[c];
        const float* gp = g4 + (size_t)c * 65536;
        float gv = w00 * gp[s00] + w01 * gp[s01] + w10 * gp[s10] + w11 * gp[s11];
        float s = gv * ape;
        a0 += wb[c] * s; a1 += wb[64 + c] * s; a2 += wb[128 + c] * s;
    }
    float f0 = w00 * h3[s00] + w01 * h3[s01] + w10 * h3[s10] + w11 * h3[s11];
    const float* h1 = h3 + 65536;
    float f1 = w00 * h1[s00] + w01 * h1[s01] + w10 * h1[s10] + w11 * h1[s11];
    const float* h2 = h3 + 131072;
    float f2 = w00 * h2[s00] + w01 * h2[s01] + w10 * h2[s10] + w11 * h2[s11];
    out[p]            = a0 + f0 + bcs[0] + x0;
    out[NPIX + p]     = a1 + f1 + bcs[1] + x1;
    out[2 * NPIX + p] = a2 + f2 + bcs[2] + x2;
}

// ================================================================ launcher
extern "C" void kernel_launch(void* const* d_in, const int* in_sizes, int n_in,
                              void* d_out, int out_size, void* d_ws, size_t ws_size,
                              hipStream_t stream) {
    const float* x      = (const float*)d_in[0];
    const float* w_cf1  = (const float*)d_in[1];  const float* b_cf1 = (const float*)d_in[2];
    const float* w_e1   = (const float*)d_in[3];  const float* b_e1  = (const float*)d_in[4];
    const float* w_e2   = (const float*)d_in[5];  const float* b_e2  = (const float*)d_in[6];
    const float* w_d1   = (const float*)d_in[7];  const float* b_d1  = (const float*)d_in[8];
    const float* w_d2   = (const float*)d_in[9];  const float* b_d2  = (const float*)d_in[10];
    // 11..14: pha branch is dead code in the reference
    const float* w_amp1 = (const float*)d_in[15]; const float* b_amp1 = (const float*)d_in[16];
    const float* w_amp2 = (const float*)d_in[17]; const float* b_amp2 = (const float*)d_in[18];
    const float* w_sp1  = (const float*)d_in[19]; const float* b_sp1  = (const float*)d_in[20];
    const float* w_sp2  = (const float*)d_in[21]; const float* b_sp2  = (const float*)d_in[22];
    const float* w_u1   = (const float*)d_in[23]; const float* b_u1   = (const float*)d_in[24];
    const float* w_u2   = (const float*)d_in[25]; const float* b_u2   = (const float*)d_in[26];
    const float* w_u3   = (const float*)d_in[27]; const float* b_u3   = (const float*)d_in[28];
    const float* w_u4   = (const float*)d_in[29]; const float* b_u4   = (const float*)d_in[30];
    const float* w_cf2  = (const float*)d_in[31]; const float* b_cf2  = (const float*)d_in[32];
    const float* w_cf3  = (const float*)d_in[33]; const float* b_cf3  = (const float*)d_in[34];
    float* out = (float*)d_out;

    char* ws = (char*)d_ws;
    constexpr size_t MiB = 1ull << 20;
    float*  dark   = (float*)(ws + 0 * MiB);
    float*  tmp    = (float*)(ws + 1 * MiB);
    int*    gmax   = (int*)  (ws + 2 * MiB);
    float*  Wc     = (float*)(ws + 2 * MiB + 1024);
    float*  bc     = (float*)(ws + 2 * MiB + 2560);
    float*  W21c   = (float*)(ws + 2 * MiB + 4096);
    float*  b21c   = (float*)(ws + 2 * MiB + 7168);
    float*  b43    = (float*)(ws + 2 * MiB + 7424);
    unsigned short* d1ch = (unsigned short*)(ws + 3 * MiB);       // bf16 [128][32]
    float*  b1c    = (float*)(ws + 3 * MiB + 16384);
    float*  Uf     = (float*)(ws + 3 * MiB + 32768);              // fp32 [64][256]
    unsigned short* Wg = (unsigned short*)(ws + 3 * MiB + 131072);// bf16 [64][256]
    float*  bgc    = (float*)(ws + 3 * MiB + 196608);
    unsigned short* xd1 = (unsigned short*)(ws + 67 * MiB);   // bf16 [128][65536] = 16 MiB
    unsigned short* xd2 = (unsigned short*)(ws + 99 * MiB);   // bf16 [256][16384] =  8 MiB
    unsigned short* F1T = (unsigned short*)(ws + 115 * MiB);  // bf16 [32768][256] = 16 MiB
    float*  F2C    = (float*)(ws + 147 * MiB);                // fp32 (feeds sqrt fused in amp1)
    float*  A1     = (float*)(ws + 173 * MiB);
    float*  A2     = (float*)(ws + 182 * MiB);
    unsigned short* Zbuf = (unsigned short*)(ws + 115 * MiB); // bf16 (F1T dead after F2)
    unsigned short* I1T  = (unsigned short*)(ws + 132 * MiB); // bf16 [16640][256] = 8.5 MiB
    float*  I2T    = (float*)(ws + 149 * MiB);                // fp32 (feeds h3s fp32 dot)
    float*  h3s    = (float*)(ws + 11 * MiB);
    float*  h3     = (float*)(ws + 27 * MiB);
    unsigned short* s1 = (unsigned short*)(ws + 31 * MiB);    // bf16 [256][16384] = 8 MiB
    float*  g4out  = (float*)(ws + 71 * MiB);
    float*  g4s    = (float*)(ws + 87 * MiB);
    unsigned short* wb16 = (unsigned short*)(ws + 192 * MiB);
    unsigned short* d2h = wb16 + 65536,   * d2l = wb16 + 196608;
    unsigned short* a1h = wb16 + 327680,  * a1l = wb16 + 393216;
    unsigned short* a2h = wb16 + 458752,  * a2l = wb16 + 524288;
    unsigned short* s1h = wb16 + 589824;
    unsigned short* BfH = wb16 + 786432,  * BfL = wb16 + 819200;
    unsigned short* BfcH = wb16 + 851968, * BfcL = wb16 + 917504;
    unsigned short* BicH = wb16 + 983040, * BicL = wb16 + 1048576;
    unsigned short* BirH = wb16 + 1114112,* BirL = wb16 + 1134592;
    float* zbias = (float*)(ws + 195 * MiB + 512 * 1024);

    // 1) dark channel + gmax ; split prep kernels
    k_mrow<<<512, 256, 0, stream>>>(x, tmp, gmax);
    k_mincol_max<<<1024, 256, 0, stream>>>(tmp, dark, gmax);
    k_prepw<<<1280, 256, 0, stream>>>(w_d2, d2h, d2l, w_amp1, a1h, a1l, w_amp2, a2h, a2l, w_sp1, s1h);
    k_prepf<<<720, 256, 0, stream>>>(BfH, BfL, BfcH, BfcL, BicH, BicL, BirH, BirL, zbias);
    k_prepu<<<64, 256, 0, stream>>>(w_u3, w_u4, Uf);
    k_prepc<<<18, 256, 0, stream>>>(
        w_e1, b_e1, w_e2, b_e2, w_d1, b_d1, d1ch, b1c,
        w_cf2, b_cf2, w_cf3, b_cf3, w_u2, b_u2, w_u1, b_u1, Wc, bc, W21c, b21c);
    k_prepb43<<<1, 64, 0, stream>>>(w_u4, b_u3, b_u4, b43);
    k_prep2<<<64, 256, 0, stream>>>(Uf, w_sp2, b_sp2, b43, Wg, bgc);

    // 2) composed d1 = (w_d1∘w_e2∘w_e1) on 2x2 x-patches, K=12→32 ; d2
    k_mmcf<2, 0, 0, 0, 0, 1><<<1024, 256, 0, stream>>>(x, d1ch, nullptr, b1c, xd1, 65536, 128, 32, 0, 0, 0, 2);
    k_mmcf<1, 0, 0, 0, 1, 1><<<512, 256, 0, stream>>>(xd1, d2h, nullptr, b_d2, xd2, 16384, 256, 512, 7, 7, 256, 4);

    // 3) FFT section (amp = sqrt fused into amp1 A-stage)
    k_mmcf<3, 0, 0, 1, 1, 1><<<1024, 256, 0, stream>>>(xd2, BfH, nullptr, zbias, F1T, 32768, 256, 128, 0, 0, 0, 4);
    k_mmcf<7, 0, 0, 0, 1, 0><<<520, 256, 0, stream>>>(F1T, BfcH, nullptr, zbias, F2C, 16640, 256, 256, 0, 0, 0, 4);
    k_mmcf<9, 1, 1, 0, 0, 0><<<260, 256, 0, stream>>>(F2C, a1h, a1l, b_amp1, A1, 8320, 256, 256, 0, 0, 0, 4);
    k_mmcf<0, 1, 0, 0, 0, 0><<<260, 256, 0, stream>>>(A1, a2h, a2l, b_amp2, A2, 8320, 256, 256, 0, 0, 0, 4);
    k_zbuild<<<8320, 256, 0, stream>>>(A2, Zbuf);
    k_mmcf<0, 0, 0, 1, 1, 1><<<520, 256, 0, stream>>>(Zbuf, BicH, nullptr, zbias, I1T, 16640, 256, 256, 0, 0, 0, 4);
    k_mmcf<8, 0, 0, 1, 1, 0><<<512, 256, 0, stream>>>(I1T, BirH, nullptr, zbias, I2T, 32768, 128, 160, 0, 0, 0, 2);

    // 4) four path: h3s = W21c @ I2T ; resize 3ch
    k_h3s<<<256, 64, 0, stream>>>(I2T, W21c, b21c, h3s);
    k_resize2<<<768, 256, 0, stream>>>(h3s, h3, 3, 128);

    // 5) spat path: sp1 ; composed (u4·u3·sp2) GEMM ; resize 64ch
    k_mmcf<0, 0, 1, 0, 1, 1><<<512, 256, 0, stream>>>(xd2, s1h, nullptr, b_sp1, s1, 16384, 256, 256, 0, 0, 0, 4);
    k_mmcf<0, 0, 0, 0, 1, 0><<<128, 256, 0, stream>>>(s1, Wg, nullptr, bgc, g4s, 16384, 64, 256, 0, 0, 0, 1);
    k_resize2<<<16384, 256, 0, stream>>>(g4s, g4out, 64, 128);

    // 6) final fused stage
    k_final<<<1024, 256, 0, stream>>>(x, dark, gmax, w_cf1, b_cf1, Wc, bc, g4out, h3, out);
}

// Round 5
// 374.504 us; speedup vs baseline: 1.0416x; 1.0416x over previous
//
#include <hip/hip_runtime.h>
#include <math.h>

#define PI_F 3.14159265358979323846f
#define NPIX 262144   // 512*512

typedef __attribute__((ext_vector_type(8))) short sh8;
typedef __attribute__((ext_vector_type(4))) float fx4;
typedef __attribute__((ext_vector_type(4))) unsigned short ush4;

__device__ __forceinline__ unsigned short f2bf(float v) {
    unsigned u = __float_as_uint(v);
    return (unsigned short)((u + 0x7FFFu + ((u >> 16) & 1)) >> 16);
}
__device__ __forceinline__ float bf2f(unsigned short h) {
    return __uint_as_float((unsigned)h << 16);
}

__device__ __forceinline__ int refl512(int t) {
    if (t < 0) t = -t;
    if (t > 511) t = 1022 - t;
    return t;
}

// ---------------------------------------------------------------- dark channel (fused min-c + row-min)
__global__ __launch_bounds__(256) void k_mrow(const float* __restrict__ x, float* __restrict__ tmp,
                                              int* __restrict__ gmax) {
    __shared__ float row[512];
    int i = blockIdx.x, tid = threadIdx.x;
    if (i == 0 && tid == 0) gmax[0] = 0;
    #pragma unroll
    for (int h = 0; h < 2; h++) {
        int j = tid + h * 256;
        int p = (i << 9) + j;
        float m = fmaxf(x[p], fmaxf(x[p + NPIX], x[p + 2 * NPIX]));
        row[j] = 1.0f - m;
    }
    __syncthreads();
    #pragma unroll
    for (int h = 0; h < 2; h++) {
        int j = tid + h * 256;
        float m = 1e30f;
        #pragma unroll
        for (int d = -7; d <= 7; d++) m = fminf(m, row[refl512(j + d)]);
        tmp[(i << 9) + j] = m;
    }
}

__global__ __launch_bounds__(256) void k_mincol_max(const float* __restrict__ tmp, float* __restrict__ dark,
                                                    int* __restrict__ gmax) {
    int p = blockIdx.x * 256 + threadIdx.x;
    int i = p >> 9, j = p & 511;
    float m = 1e30f;
    #pragma unroll
    for (int d = -7; d <= 7; d++) m = fminf(m, tmp[(refl512(i + d) << 9) + j]);
    dark[p] = m;
    __shared__ float red[256];
    int tid = threadIdx.x;
    red[tid] = m;
    __syncthreads();
    for (int s = 128; s > 0; s >>= 1) {
        if (tid < s) red[tid] = fmaxf(red[tid], red[tid + s]);
        __syncthreads();
    }
    if (tid == 0) atomicMax(gmax, __float_as_int(red[0]));
}

// ---------------------------------------------------------------- prep helpers (device)
__device__ __forceinline__ void prep_one(const float* __restrict__ w, unsigned short* __restrict__ h,
                                         unsigned short* __restrict__ l, int N, int K, int cshift, int idx) {
    if (idx >= N * K) return;
    int n = idx / K, kord = idx - n * K;
    int ksrc = kord;
    if (cshift) {
        int dydx = kord >> cshift, c = kord & ((1 << cshift) - 1);
        ksrc = c * 4 + dydx;
    }
    float v = w[n * K + ksrc];
    unsigned short hb = f2bf(v);
    h[idx] = hb;
    if (l) l[idx] = f2bf(v - bf2f(hb));
}

// ---------------------------------------------------------------- prepA: weight rounding + DFT tables
__global__ __launch_bounds__(256) void k_prepA(
    const float* __restrict__ w_d2, unsigned short* __restrict__ d2h, unsigned short* __restrict__ d2l,
    const float* __restrict__ w_a1, unsigned short* __restrict__ a1h, unsigned short* __restrict__ a1l,
    const float* __restrict__ w_a2, unsigned short* __restrict__ a2h, unsigned short* __restrict__ a2l,
    const float* __restrict__ w_s1, unsigned short* __restrict__ s1h,
    unsigned short* __restrict__ BfH, unsigned short* __restrict__ BfL,
    unsigned short* __restrict__ BfcH, unsigned short* __restrict__ BfcL,
    unsigned short* __restrict__ BicH, unsigned short* __restrict__ BicL,
    unsigned short* __restrict__ BirH, unsigned short* __restrict__ BirL,
    float* __restrict__ zbias) {
    int b = blockIdx.x, tid = threadIdx.x;
    if (b < 512)       { prep_one(w_d2, d2h, d2l, 256, 512, 7, b * 256 + tid); return; }
    else if (b < 768)  { prep_one(w_a1, a1h, a1l, 256, 256, 0, (b - 512) * 256 + tid); return; }
    else if (b < 1024) { prep_one(w_a2, a2h, a2l, 256, 256, 0, (b - 768) * 256 + tid); return; }
    else if (b < 1280) { prep_one(w_s1, s1h, nullptr, 256, 256, 0, (b - 1024) * 256 + tid); return; }
    int idx = (b - 1280) * 256 + tid;
    if (idx < 256) zbias[idx] = 0.f;
    const float w0 = 2.f * PI_F / 128.f;
    float v;
    unsigned short *H, *L;
    int off;
    if (idx < 32768) {                     // Bf [256][128]
        int n = idx >> 7, k = idx & 127;
        int t = n & 127, r = (t * k) & 127;
        float s_, c_; sincosf(w0 * r, &s_, &c_);
        v = (n < 128) ? c_ : -s_;
        H = BfH; L = BfL; off = idx;
    } else if (idx < 98304) {              // Bfc [256][256]
        int i = idx - 32768;
        int n = i >> 8, j = i & 255;
        int t = n & 127, r = (t * (j & 127)) & 127;
        float s_, c_; sincosf(w0 * r, &s_, &c_);
        v = (n < 128) ? ((j < 128) ? c_ : s_) : ((j < 128) ? -s_ : c_);
        H = BfcH; L = BfcL; off = i;
    } else if (idx < 163840) {             // Bic [256][256]
        int i = idx - 98304;
        int n = i >> 8, j = i & 255;
        int t = n & 127, r = (t * (j & 127)) & 127;
        float s_, c_; sincosf(w0 * r, &s_, &c_);
        v = ((n < 128) ? ((j < 128) ? c_ : -s_) : ((j < 128) ? s_ : c_)) * (1.f / 128.f);
        H = BicH; L = BicL; off = i;
    } else if (idx < 184320) {             // Bir [128][160]
        int i = idx - 163840;
        int col = i / 160, j = i - col * 160;
        if (j == 0) v = 1.f / 128.f;
        else if (j < 64)  { int r = (j * col) & 127; float s_, c_; sincosf(w0 * r, &s_, &c_); v = 2.f * c_ / 128.f; }
        else if (j == 64) v = (col & 1) ? -1.f / 128.f : 1.f / 128.f;
        else if (j >= 66 && j <= 128) { int k = j - 65; int r = (k * col) & 127; float s_, c_; sincosf(w0 * r, &s_, &c_); v = -2.f * s_ / 128.f; }
        else v = 0.f;
        H = BirH; L = BirL; off = i;
    } else return;
    unsigned short hb = f2bf(v);
    H[off] = hb;
    L[off] = f2bf(v - bf2f(hb));
}

// ---------------------------------------------------------------- prepB: all small composes
__global__ __launch_bounds__(256) void k_prepB(
    const float* __restrict__ w_u3, const float* __restrict__ w_u4, float* __restrict__ Uf,
    const float* __restrict__ w_e1, const float* __restrict__ b_e1,
    const float* __restrict__ w_e2, const float* __restrict__ b_e2,
    const float* __restrict__ w_d1, const float* __restrict__ b_d1,
    unsigned short* __restrict__ d1ch, float* __restrict__ b1c,
    const float* __restrict__ b_u3, const float* __restrict__ b_u4, float* __restrict__ b43,
    const float* __restrict__ w2, const float* __restrict__ b2,
    const float* __restrict__ w3, const float* __restrict__ b3,
    const float* __restrict__ wu2, const float* __restrict__ bu2,
    const float* __restrict__ wu1, const float* __restrict__ bu1,
    float* __restrict__ Wc, float* __restrict__ bc,
    float* __restrict__ W21c, float* __restrict__ b21c) {
    int b = blockIdx.x, tid = threadIdx.x;
    if (b < 64) {
        int idx = b * 256 + tid;
        int n = idx >> 8, j = idx & 255;
        float s = 0.f;
        #pragma unroll 16
        for (int o = 0; o < 128; o++) s += w_u4[n * 128 + o] * w_u3[o * 256 + j];
        Uf[idx] = s;
    } else if (b < 80) {
        __shared__ float E[192];
        if (tid < 192) {
            int o = tid / 3, ci = tid - o * 3;
            float s = 0.f;
            #pragma unroll
            for (int r = 0; r < 8; r++) s += w_e2[o * 8 + r] * w_e1[r * 3 + ci];
            E[tid] = s;
        }
        __syncthreads();
        int idx = (b - 64) * 256 + tid;    // < 4096
        int n = idx >> 5, k = idx & 31;
        float s = 0.f;
        if (k < 12) {
            int dydx = k / 3, ci = k - dydx * 3;
            #pragma unroll 16
            for (int o = 0; o < 64; o++) s += w_d1[n * 256 + o * 4 + dydx] * E[o * 3 + ci];
        }
        d1ch[idx] = f2bf(s);
    } else if (b == 80) {
        __shared__ float f[64];
        if (tid < 64) {
            int o = tid;
            float s = b_e2[o];
            #pragma unroll
            for (int r = 0; r < 8; r++) s += w_e2[o * 8 + r] * b_e1[r];
            f[o] = s;
        }
        __syncthreads();
        if (tid < 128) {
            float s = b_d1[tid];
            #pragma unroll 8
            for (int o = 0; o < 64; o++) {
                float fo = f[o];
                #pragma unroll
                for (int dydx = 0; dydx < 4; dydx++) s += w_d1[tid * 256 + o * 4 + dydx] * fo;
            }
            b1c[tid] = s;
        }
    } else if (b == 81) {
        if (tid < 64) {
            float s = b_u4[tid];
            #pragma unroll 16
            for (int o = 0; o < 128; o++) s += w_u4[tid * 128 + o] * b_u3[o];
            b43[tid] = s;
        }
    } else {
        __shared__ float sWc[384], sW2c[384];
        if (tid < 128) {
            int j = tid;
            for (int r = 0; r < 3; r++) {
                float s = 0.f;
                #pragma unroll 16
                for (int o = 0; o < 64; o++) s += w3[r * 64 + o] * w2[o * 128 + j];
                sWc[r * 128 + j] = s;
                Wc[r * 128 + j] = s;
            }
            if (j < 3) {
                float s = b3[j];
                #pragma unroll 16
                for (int o = 0; o < 64; o++) s += w3[j * 64 + o] * b2[o];
                bc[j] = s;
            }
        }
        __syncthreads();
        if (tid < 128) {
            int j = tid;
            for (int r = 0; r < 3; r++) {
                float s = 0.f;
                #pragma unroll 16
                for (int o = 0; o < 64; o++) s += sWc[r * 128 + o] * wu2[o * 128 + j];
                sW2c[r * 128 + j] = s;
            }
        }
        __syncthreads();
        if (tid < 256) {
            int j = tid;
            for (int r = 0; r < 3; r++) {
                float s = 0.f;
                #pragma unroll 16
                for (int o = 0; o < 128; o++) s += sW2c[r * 128 + o] * wu1[o * 256 + j];
                W21c[r * 256 + j] = s;
            }
        }
        if (tid < 3) {
            float s = 0.f;
            #pragma unroll 16
            for (int o = 0; o < 128; o++) s += sW2c[tid * 128 + o] * bu1[o];
            #pragma unroll 16
            for (int o = 0; o < 64; o++)  s += sWc[tid * 128 + o] * bu2[o];
            b21c[tid] = s;
        }
    }
}

// ---------------------------------------------------------------- Wg = (u4·u3)·w_sp2 compose, b_g fold
__global__ __launch_bounds__(256) void k_prep2(const float* __restrict__ Uf, const float* __restrict__ wsp2,
                                               const float* __restrict__ bsp2, const float* __restrict__ b43,
                                               unsigned short* __restrict__ Wg, float* __restrict__ bgc) {
    __shared__ float u[256], red[256];
    int n = blockIdx.x, tid = threadIdx.x;
    u[tid] = Uf[n * 256 + tid];
    __syncthreads();
    float s = 0.f;
    #pragma unroll 16
    for (int o = 0; o < 256; o++) s += u[o] * wsp2[o * 256 + tid];
    Wg[n * 256 + tid] = f2bf(s);
    red[tid] = u[tid] * bsp2[tid];
    __syncthreads();
    for (int st = 128; st > 0; st >>= 1) {
        if (tid < st) red[tid] += red[tid + st];
        __syncthreads();
    }
    if (tid == 0) bgc[n] = b43[n] + red[0];
}

// ---------------------------------------------------------------- channels-first MFMA GEMM
template<int AMODE, int SPLIT, int LRELU, int TSTORE, int ABF16, int CBF16>
__global__ __launch_bounds__(256) void k_mmcf(const void* __restrict__ Asrc_,
                                              const unsigned short* __restrict__ Bh,
                                              const unsigned short* __restrict__ Bl,
                                              const float* __restrict__ bias, void* __restrict__ C_,
                                              int M, int N, int K, int cshift, int wshift, int srcW,
                                              int gy) {
    const float* Af = (const float*)Asrc_;
    const unsigned short* A16 = (const unsigned short*)Asrc_;
    float* Cf = (float*)C_;
    unsigned short* C16 = (unsigned short*)C_;
    __shared__ unsigned short AhS[128 * 40];
    __shared__ unsigned short BhS[64 * 40];
    __shared__ unsigned short AlS[SPLIT ? 128 * 40 : 8];
    __shared__ unsigned short BlS[SPLIT ? 64 * 40 : 8];
    int tid = threadIdx.x;
    int nwg = (int)gridDim.x;
    int bid = blockIdx.x;
    int qq = nwg >> 3, rr = nwg & 7;
    int xcd = bid & 7, ixw = bid >> 3;
    int work = (xcd < rr) ? (xcd * (qq + 1) + ixw) : (rr * (qq + 1) + (xcd - rr) * qq + ixw);
    int bx = work / gy;
    int by = work - bx * gy;
    int m0 = bx * 128;
    int n0 = by * 64;
    int wave = tid >> 6, lane = tid & 63;
    int wm = (wave >> 1) * 64, wn = (wave & 1) * 32;
    int l15 = lane & 15, quad = lane >> 4;
    int lk = quad * 8, lk4 = quad * 4;
    fx4 acc[4][2];
    #pragma unroll
    for (int a = 0; a < 4; a++)
        #pragma unroll
        for (int b = 0; b < 2; b++)
            acc[a][b] = (fx4){0.f, 0.f, 0.f, 0.f};

    int mm = tid & 127;
    int kpb = tid >> 7;
    int gm = m0 + mm;
    int oj = 0, oi = 0, cA = 0, kfA = 0, tauA = 0;
    size_t abase = 0;
    if (AMODE == 1) { oj = gm & ((1 << wshift) - 1); oi = gm >> wshift; }
    if (AMODE == 2) { oj = gm & 255; oi = gm >> 8; }
    if (AMODE == 3) abase = (size_t)gm * K;
    if (AMODE == 7) { cA = gm / 65; kfA = gm - cA * 65; }
    if (AMODE == 8) { cA = gm >> 7; tauA = gm & 127; }
    if (AMODE == 9) { cA = gm / 65; kfA = gm - cA * 65; }

    for (int kb = 0; kb < K; kb += 32) {
        if (AMODE == 3 && ABF16 && !SPLIT) {
            #pragma unroll
            for (int half = 0; half < 2; half++) {
                sh8 hv = *(const sh8*)(const void*)&A16[abase + kb + kpb * 16 + half * 8];
                *(sh8*)(void*)&AhS[mm * 40 + (kpb * 2 + half) * 8] = hv;
            }
        } else {
            #pragma unroll
            for (int half = 0; half < 2; half++) {
                sh8 hv, lv;
                #pragma unroll
                for (int tt = 0; tt < 4; tt++) {
                    int kp = kpb * 8 + half * 4 + tt;
                    int k0 = kb + kp * 2;
                    unsigned short h0, h1;
                    if (ABF16) {
                        size_t ad0, ad1;
                        if (AMODE == 0) {
                            ad0 = (size_t)k0 * M + gm;
                            ad1 = ad0 + M;
                        } else if (AMODE == 1) {
                            int c = k0 & ((1 << cshift) - 1);
                            int dydx = k0 >> cshift;
                            int dy = dydx >> 1, dx = dydx & 1;
                            size_t pix = (size_t)(2 * oi + dy) * srcW + (2 * oj + dx);
                            size_t plane = (size_t)srcW * srcW;
                            ad0 = (size_t)c * plane + pix;
                            ad1 = ad0 + plane;
                        } else if (AMODE == 3) {
                            ad0 = abase + k0;
                            ad1 = ad0 + 1;
                        } else if (AMODE == 7) {
                            int t0 = k0 & 127, hf = k0 >> 7;
                            ad0 = (size_t)(cA * 128 + t0) * 256 + hf * 128 + kfA;
                            ad1 = ad0 + 256;
                        } else {               // AMODE 8
                            int j0 = k0, j1 = k0 + 1;
                            int kf0 = (j0 < 65) ? j0 : ((j0 < 130) ? j0 - 65 : 0);
                            int hf0 = (j0 >= 65 && j0 < 130) ? 1 : 0;
                            int kf1 = (j1 < 65) ? j1 : ((j1 < 130) ? j1 - 65 : 0);
                            int hf1 = (j1 >= 65 && j1 < 130) ? 1 : 0;
                            ad0 = (size_t)(cA * 65 + kf0) * 256 + hf0 * 128 + tauA;
                            ad1 = (size_t)(cA * 65 + kf1) * 256 + hf1 * 128 + tauA;
                        }
                        h0 = A16[ad0];
                        h1 = A16[ad1];
                    } else {
                        float a0, a1;
                        if (AMODE == 2) {
                            if (k0 < 12) {
                                int d0 = k0 / 3, c0 = k0 - d0 * 3;
                                int k1 = k0 + 1;
                                int d1x = k1 / 3, c1 = k1 - d1x * 3;
                                a0 = Af[(size_t)c0 * NPIX + (size_t)(2 * oi + (d0 >> 1)) * 512 + 2 * oj + (d0 & 1)];
                                a1 = Af[(size_t)c1 * NPIX + (size_t)(2 * oi + (d1x >> 1)) * 512 + 2 * oj + (d1x & 1)];
                            } else { a0 = 0.f; a1 = 0.f; }
                        } else if (AMODE == 9) {
                            size_t ad = (size_t)cA * 16640 + (size_t)k0 * 65 + kfA;
                            float re0 = Af[ad], im0 = Af[ad + 2129920];
                            float re1 = Af[ad + 65], im1 = Af[ad + 65 + 2129920];
                            a0 = sqrtf(re0 * re0 + im0 * im0);
                            a1 = sqrtf(re1 * re1 + im1 * im1);
                        } else {
                            size_t ad0 = (size_t)k0 * M + gm;
                            a0 = Af[ad0];
                            a1 = Af[ad0 + M];
                        }
                        h0 = f2bf(a0);
                        h1 = f2bf(a1);
                        if (SPLIT) {
                            lv[tt * 2] = (short)f2bf(a0 - bf2f(h0));
                            lv[tt * 2 + 1] = (short)f2bf(a1 - bf2f(h1));
                        }
                    }
                    hv[tt * 2] = (short)h0;
                    hv[tt * 2 + 1] = (short)h1;
                }
                int coff = (kpb * 2 + half) * 8;
                *(sh8*)(void*)&AhS[mm * 40 + coff] = hv;
                if (SPLIT) *(sh8*)(void*)&AlS[mm * 40 + coff] = lv;
            }
        }
        {
            int n = tid >> 2, seg = tid & 3;
            size_t gb = (size_t)(n0 + n) * K + kb + seg * 8;
            *(sh8*)(void*)&BhS[n * 40 + seg * 8] = *(const sh8*)(const void*)&Bh[gb];
            if (SPLIT) *(sh8*)(void*)&BlS[n * 40 + seg * 8] = *(const sh8*)(const void*)&Bl[gb];
        }
        __syncthreads();
        sh8 af[4], bf[2], afl[4], bfl[2];
        #pragma unroll
        for (int mt = 0; mt < 4; mt++) {
            af[mt] = *(const sh8*)(const void*)&AhS[(wm + mt * 16 + l15) * 40 + lk];
            if (SPLIT) afl[mt] = *(const sh8*)(const void*)&AlS[(wm + mt * 16 + l15) * 40 + lk];
        }
        #pragma unroll
        for (int nt = 0; nt < 2; nt++) {
            bf[nt] = *(const sh8*)(const void*)&BhS[(wn + nt * 16 + l15) * 40 + lk];
            if (SPLIT) bfl[nt] = *(const sh8*)(const void*)&BlS[(wn + nt * 16 + l15) * 40 + lk];
        }
        #pragma unroll
        for (int mt = 0; mt < 4; mt++)
            #pragma unroll
            for (int nt = 0; nt < 2; nt++) {
                acc[mt][nt] = __builtin_amdgcn_mfma_f32_16x16x32_bf16(af[mt], bf[nt], acc[mt][nt], 0, 0, 0);
                if (SPLIT) {
                    acc[mt][nt] = __builtin_amdgcn_mfma_f32_16x16x32_bf16(af[mt], bfl[nt], acc[mt][nt], 0, 0, 0);
                    acc[mt][nt] = __builtin_amdgcn_mfma_f32_16x16x32_bf16(afl[mt], bf[nt], acc[mt][nt], 0, 0, 0);
                }
            }
        __syncthreads();
    }
    #pragma unroll
    for (int nt = 0; nt < 2; nt++) {
        int n = n0 + wn + nt * 16 + l15;
        float bs = bias[n];
        #pragma unroll
        for (int mt = 0; mt < 4; mt++) {
            int mbase = m0 + wm + mt * 16 + lk4;
            if (TSTORE) {
                #pragma unroll
                for (int r = 0; r < 4; r++) {
                    float q = acc[mt][nt][r] + bs;
                    if (LRELU) q = (q < 0.f) ? 0.1f * q : q;
                    if (CBF16) C16[(size_t)(mbase + r) * N + n] = f2bf(q);
                    else       Cf[(size_t)(mbase + r) * N + n] = q;
                }
            } else if (CBF16) {
                ush4 v;
                #pragma unroll
                for (int r = 0; r < 4; r++) {
                    float q = acc[mt][nt][r] + bs;
                    if (LRELU) q = (q < 0.f) ? 0.1f * q : q;
                    v[r] = f2bf(q);
                }
                *(ush4*)(void*)&C16[(size_t)n * M + mbase] = v;
            } else {
                float4 v;
                float* vp = (float*)&v;
                #pragma unroll
                for (int r = 0; r < 4; r++) {
                    float q = acc[mt][nt][r] + bs;
                    if (LRELU) q = (q < 0.f) ? 0.1f * q : q;
                    vp[r] = q;
                }
                *(float4*)&Cf[(size_t)n * M + mbase] = v;
            }
        }
    }
}

// ---------------------------------------------------------------- z = a*(cos a, sin a), flattened full-wave, bf16
__global__ __launch_bounds__(256) void k_zbuild(const float* __restrict__ A2, unsigned short* __restrict__ Z) {
    int idx = blockIdx.x * 256 + threadIdx.x;   // < 2129920
    int ct = idx / 65, kf = idx - ct * 65;
    int c = ct >> 7, t = ct & 127;
    float a = A2[idx];
    float s_, c_;
    sincosf(a, &s_, &c_);
    size_t m = (size_t)c * 65 + kf;
    Z[(size_t)t * 16640 + m] = f2bf(a * c_);
    Z[2129920 + (size_t)t * 16640 + m] = f2bf(a * s_);
}

// ---------------------------------------------------------------- h3s = W21c @ I2T + b21c  (3ch @128^2, K=256)
__global__ __launch_bounds__(64) void k_h3s(const float* __restrict__ I2T, const float* __restrict__ W21c,
                                            const float* __restrict__ b21c, float* __restrict__ h3s) {
    __shared__ float wa[768], bs[3];
    int tid = threadIdx.x;
    for (int i = tid; i < 768; i += 64) wa[i] = W21c[i];
    if (tid < 3) bs[tid] = b21c[tid];
    __syncthreads();
    int q = blockIdx.x * 64 + tid;
    float a0 = bs[0], a1 = bs[1], a2 = bs[2];
    #pragma unroll 4
    for (int c = 0; c < 256; c++) {
        float v = I2T[(size_t)c * 16384 + q];
        a0 += wa[c] * v;
        a1 += wa[256 + c] * v;
        a2 += wa[512 + c] * v;
    }
    h3s[q] = a0; h3s[16384 + q] = a1; h3s[32768 + q] = a2;
}

// ---------------------------------------------------------------- final fused stage @512^2
// Double-bilinear (128->256->512) composed into a closed-form 3-tap/axis stencil:
//   k=i>>2, r=i&3; taps (k-1,k,k+1) clamped to [0,127];
//   weights: r=0 (.375,.625,0) r=1 (.1875,.75,.0625) r=2 (.0625,.75,.1875) r=3 (0,.625,.375)
// Verified to match chained k_resize2 + 4-tap exactly incl. edges (clamped weight folds onto clamped index).
__global__ __launch_bounds__(256) void k_final(const float* __restrict__ x,
                                               const float* __restrict__ dark, const int* __restrict__ gmax,
                                               const float* __restrict__ wcf1, const float* __restrict__ bcf1,
                                               const float* __restrict__ Wc, const float* __restrict__ bc,
                                               const float* __restrict__ g4s, const float* __restrict__ h3s,
                                               float* __restrict__ out) {
    __shared__ float dimt[32], w1[192], b1[64], wb[192], bcs[3];
    int tid = threadIdx.x;
    if (tid < 32) dimt[tid] = powf(10000.f, (float)(2 * (tid >> 1)) / 32.f);
    if (tid < 192) w1[tid] = wcf1[tid];
    if (tid < 64) b1[tid] = bcf1[tid];
    if (tid < 192) { int r = tid / 64, c = tid - (tid / 64) * 64; wb[tid] = Wc[r * 128 + 64 + c]; }
    if (tid < 3) bcs[tid] = bc[tid];
    __syncthreads();
    int p = blockIdx.x * 256 + threadIdx.x;
    int i = p >> 9, j = p & 511;
    const float scale = 2.f * PI_F;
    float inv511 = scale / (511.f + 1e-6f);
    float xe = (float)j * inv511, ye = (float)i * inv511;
    float gm = __int_as_float(gmax[0]);
    float ze = dark[p] / (gm + 1e-6f) * scale;
    float x0 = x[p], x1 = x[p + NPIX], x2 = x[p + 2 * NPIX];

    // composite 512->128 taps (y axis)
    int ky = i >> 2, ry = i & 3;
    int ym = (ky > 0) ? ky - 1 : 0, yp = (ky < 127) ? ky + 1 : 127;
    float wy0 = (ry == 0) ? .375f : (ry == 1) ? .1875f : (ry == 2) ? .0625f : 0.f;
    float wy1 = (ry == 0 || ry == 3) ? .625f : .75f;
    float wy2 = (ry == 0) ? 0.f : (ry == 1) ? .0625f : (ry == 2) ? .1875f : .375f;
    // x axis
    int kx = j >> 2, rx = j & 3;
    int xm = (kx > 0) ? kx - 1 : 0, xp = (kx < 127) ? kx + 1 : 127;
    float wx0 = (rx == 0) ? .375f : (rx == 1) ? .1875f : (rx == 2) ? .0625f : 0.f;
    float wx1 = (rx == 0 || rx == 3) ? .625f : .75f;
    float wx2 = (rx == 0) ? 0.f : (rx == 1) ? .0625f : (rx == 2) ? .1875f : .375f;
    int r0 = ym * 128, r1 = ky * 128, r2 = yp * 128;
    int o00 = r0 + xm, o01 = r0 + kx, o02 = r0 + xp;
    int o10 = r1 + xm, o11 = r1 + kx, o12 = r1 + xp;
    int o20 = r2 + xm, o21 = r2 + kx, o22 = r2 + xp;

    float a0 = 0.f, a1 = 0.f, a2 = 0.f;
    #pragma unroll 1
    for (int c = 0; c < 64; c++) {
        float e = (c < 16) ? xe / dimt[c] : (c < 32) ? ye / dimt[c - 16] : ze / dimt[c - 32];
        float sn, cs;
        __sincosf(e, &sn, &cs);
        float pos = ((c & 1) == 0) ? sn : cs;
        float ape = pos + w1[c * 3] * x0 + w1[c * 3 + 1] * x1 + w1[c * 3 + 2] * x2 + b1[c];
        const float* gp = g4s + (size_t)c * 16384;
        float gv = wy0 * (wx0 * gp[o00] + wx1 * gp[o01] + wx2 * gp[o02])
                 + wy1 * (wx0 * gp[o10] + wx1 * gp[o11] + wx2 * gp[o12])
                 + wy2 * (wx0 * gp[o20] + wx1 * gp[o21] + wx2 * gp[o22]);
        float s = gv * ape;
        a0 += wb[c] * s; a1 += wb[64 + c] * s; a2 += wb[128 + c] * s;
    }
    float f0, f1, f2;
    {
        const float* hp = h3s;
        f0 = wy0 * (wx0 * hp[o00] + wx1 * hp[o01] + wx2 * hp[o02])
           + wy1 * (wx0 * hp[o10] + wx1 * hp[o11] + wx2 * hp[o12])
           + wy2 * (wx0 * hp[o20] + wx1 * hp[o21] + wx2 * hp[o22]);
        hp = h3s + 16384;
        f1 = wy0 * (wx0 * hp[o00] + wx1 * hp[o01] + wx2 * hp[o02])
           + wy1 * (wx0 * hp[o10] + wx1 * hp[o11] + wx2 * hp[o12])
           + wy2 * (wx0 * hp[o20] + wx1 * hp[o21] + wx2 * hp[o22]);
        hp = h3s + 32768;
        f2 = wy0 * (wx0 * hp[o00] + wx1 * hp[o01] + wx2 * hp[o02])
           + wy1 * (wx0 * hp[o10] + wx1 * hp[o11] + wx2 * hp[o12])
           + wy2 * (wx0 * hp[o20] + wx1 * hp[o21] + wx2 * hp[o22]);
    }
    out[p]            = a0 + f0 + bcs[0] + x0;
    out[NPIX + p]     = a1 + f1 + bcs[1] + x1;
    out[2 * NPIX + p] = a2 + f2 + bcs[2] + x2;
}

// ================================================================ launcher
extern "C" void kernel_launch(void* const* d_in, const int* in_sizes, int n_in,
                              void* d_out, int out_size, void* d_ws, size_t ws_size,
                              hipStream_t stream) {
    const float* x      = (const float*)d_in[0];
    const float* w_cf1  = (const float*)d_in[1];  const float* b_cf1 = (const float*)d_in[2];
    const float* w_e1   = (const float*)d_in[3];  const float* b_e1  = (const float*)d_in[4];
    const float* w_e2   = (const float*)d_in[5];  const float* b_e2  = (const float*)d_in[6];
    const float* w_d1   = (const float*)d_in[7];  const float* b_d1  = (const float*)d_in[8];
    const float* w_d2   = (const float*)d_in[9];  const float* b_d2  = (const float*)d_in[10];
    // 11..14: pha branch is dead code in the reference
    const float* w_amp1 = (const float*)d_in[15]; const float* b_amp1 = (const float*)d_in[16];
    const float* w_amp2 = (const float*)d_in[17]; const float* b_amp2 = (const float*)d_in[18];
    const float* w_sp1  = (const float*)d_in[19]; const float* b_sp1  = (const float*)d_in[20];
    const float* w_sp2  = (const float*)d_in[21]; const float* b_sp2  = (const float*)d_in[22];
    const float* w_u1   = (const float*)d_in[23]; const float* b_u1   = (const float*)d_in[24];
    const float* w_u2   = (const float*)d_in[25]; const float* b_u2   = (const float*)d_in[26];
    const float* w_u3   = (const float*)d_in[27]; const float* b_u3   = (const float*)d_in[28];
    const float* w_u4   = (const float*)d_in[29]; const float* b_u4   = (const float*)d_in[30];
    const float* w_cf2  = (const float*)d_in[31]; const float* b_cf2  = (const float*)d_in[32];
    const float* w_cf3  = (const float*)d_in[33]; const float* b_cf3  = (const float*)d_in[34];
    float* out = (float*)d_out;

    char* ws = (char*)d_ws;
    constexpr size_t MiB = 1ull << 20;
    float*  dark   = (float*)(ws + 0 * MiB);
    float*  tmp    = (float*)(ws + 1 * MiB);
    int*    gmax   = (int*)  (ws + 2 * MiB);
    float*  Wc     = (float*)(ws + 2 * MiB + 1024);
    float*  bc     = (float*)(ws + 2 * MiB + 2560);
    float*  W21c   = (float*)(ws + 2 * MiB + 4096);
    float*  b21c   = (float*)(ws + 2 * MiB + 7168);
    float*  b43    = (float*)(ws + 2 * MiB + 7424);
    unsigned short* d1ch = (unsigned short*)(ws + 3 * MiB);       // bf16 [128][32]
    float*  b1c    = (float*)(ws + 3 * MiB + 16384);
    float*  Uf     = (float*)(ws + 3 * MiB + 32768);              // fp32 [64][256]
    unsigned short* Wg = (unsigned short*)(ws + 3 * MiB + 131072);// bf16 [64][256]
    float*  bgc    = (float*)(ws + 3 * MiB + 196608);
    unsigned short* xd1 = (unsigned short*)(ws + 67 * MiB);   // bf16 [128][65536] = 16 MiB
    unsigned short* xd2 = (unsigned short*)(ws + 99 * MiB);   // bf16 [256][16384] =  8 MiB
    unsigned short* F1T = (unsigned short*)(ws + 115 * MiB);  // bf16 [32768][256] = 16 MiB
    float*  F2C    = (float*)(ws + 147 * MiB);                // fp32 (feeds sqrt fused in amp1)
    float*  A1     = (float*)(ws + 173 * MiB);
    float*  A2     = (float*)(ws + 182 * MiB);
    unsigned short* Zbuf = (unsigned short*)(ws + 115 * MiB); // bf16 (F1T dead after F2)
    unsigned short* I1T  = (unsigned short*)(ws + 132 * MiB); // bf16 [16640][256] = 8.5 MiB
    float*  I2T    = (float*)(ws + 149 * MiB);                // fp32 (feeds h3s fp32 dot)
    float*  h3s    = (float*)(ws + 11 * MiB);                 // fp32 [3][16384]
    unsigned short* s1 = (unsigned short*)(ws + 31 * MiB);    // bf16 [256][16384] = 8 MiB
    float*  g4s    = (float*)(ws + 87 * MiB);                 // fp32 [64][16384]
    unsigned short* wb16 = (unsigned short*)(ws + 192 * MiB);
    unsigned short* d2h = wb16 + 65536,   * d2l = wb16 + 196608;
    unsigned short* a1h = wb16 + 327680,  * a1l = wb16 + 393216;
    unsigned short* a2h = wb16 + 458752,  * a2l = wb16 + 524288;
    unsigned short* s1h = wb16 + 589824;
    unsigned short* BfH = wb16 + 786432,  * BfL = wb16 + 819200;
    unsigned short* BfcH = wb16 + 851968, * BfcL = wb16 + 917504;
    unsigned short* BicH = wb16 + 983040, * BicL = wb16 + 1048576;
    unsigned short* BirH = wb16 + 1114112,* BirL = wb16 + 1134592;
    float* zbias = (float*)(ws + 195 * MiB + 512 * 1024);

    // 1) dark channel + gmax ; merged prep (3 launches)
    k_mrow<<<512, 256, 0, stream>>>(x, tmp, gmax);
    k_mincol_max<<<1024, 256, 0, stream>>>(tmp, dark, gmax);
    k_prepA<<<2000, 256, 0, stream>>>(w_d2, d2h, d2l, w_amp1, a1h, a1l, w_amp2, a2h, a2l, w_sp1, s1h,
                                      BfH, BfL, BfcH, BfcL, BicH, BicL, BirH, BirL, zbias);
    k_prepB<<<83, 256, 0, stream>>>(w_u3, w_u4, Uf,
                                    w_e1, b_e1, w_e2, b_e2, w_d1, b_d1, d1ch, b1c,
                                    b_u3, b_u4, b43,
                                    w_cf2, b_cf2, w_cf3, b_cf3, w_u2, b_u2, w_u1, b_u1,
                                    Wc, bc, W21c, b21c);
    k_prep2<<<64, 256, 0, stream>>>(Uf, w_sp2, b_sp2, b43, Wg, bgc);

    // 2) composed d1 = (w_d1∘w_e2∘w_e1) on 2x2 x-patches, K=12→32 ; d2
    k_mmcf<2, 0, 0, 0, 0, 1><<<1024, 256, 0, stream>>>(x, d1ch, nullptr, b1c, xd1, 65536, 128, 32, 0, 0, 0, 2);
    k_mmcf<1, 0, 0, 0, 1, 1><<<512, 256, 0, stream>>>(xd1, d2h, nullptr, b_d2, xd2, 16384, 256, 512, 7, 7, 256, 4);

    // 3) FFT section (amp = sqrt fused into amp1 A-stage)
    k_mmcf<3, 0, 0, 1, 1, 1><<<1024, 256, 0, stream>>>(xd2, BfH, nullptr, zbias, F1T, 32768, 256, 128, 0, 0, 0, 4);
    k_mmcf<7, 0, 0, 0, 1, 0><<<520, 256, 0, stream>>>(F1T, BfcH, nullptr, zbias, F2C, 16640, 256, 256, 0, 0, 0, 4);
    k_mmcf<9, 1, 1, 0, 0, 0><<<260, 256, 0, stream>>>(F2C, a1h, a1l, b_amp1, A1, 8320, 256, 256, 0, 0, 0, 4);
    k_mmcf<0, 1, 0, 0, 0, 0><<<260, 256, 0, stream>>>(A1, a2h, a2l, b_amp2, A2, 8320, 256, 256, 0, 0, 0, 4);
    k_zbuild<<<8320, 256, 0, stream>>>(A2, Zbuf);
    k_mmcf<0, 0, 0, 1, 1, 1><<<520, 256, 0, stream>>>(Zbuf, BicH, nullptr, zbias, I1T, 16640, 256, 256, 0, 0, 0, 4);
    k_mmcf<8, 0, 0, 1, 1, 0><<<512, 256, 0, stream>>>(I1T, BirH, nullptr, zbias, I2T, 32768, 128, 160, 0, 0, 0, 2);

    // 4) four path: h3s = W21c @ I2T (@128^2; upsample folded into k_final)
    k_h3s<<<256, 64, 0, stream>>>(I2T, W21c, b21c, h3s);

    // 5) spat path: sp1 ; composed (u4·u3·sp2) GEMM (@128^2; upsample folded into k_final)
    k_mmcf<0, 0, 1, 0, 1, 1><<<512, 256, 0, stream>>>(xd2, s1h, nullptr, b_sp1, s1, 16384, 256, 256, 0, 0, 0, 4);
    k_mmcf<0, 0, 0, 0, 1, 0><<<128, 256, 0, stream>>>(s1, Wg, nullptr, bgc, g4s, 16384, 64, 256, 0, 0, 0, 1);

    // 6) final fused stage (double-bilinear composed 3x3 taps from g4s/h3s @128^2)
    k_final<<<1024, 256, 0, stream>>>(x, dark, gmax, w_cf1, b_cf1, Wc, bc, g4s, h3s, out);
}

// Round 6
// 356.840 us; speedup vs baseline: 1.0931x; 1.0495x over previous
//
#include <hip/hip_runtime.h>
#include <math.h>

#define PI_F 3.14159265358979323846f
#define NPIX 262144   // 512*512

typedef __attribute__((ext_vector_type(8))) short sh8;
typedef __attribute__((ext_vector_type(4))) float fx4;
typedef __attribute__((ext_vector_type(4))) unsigned short ush4;

__device__ __forceinline__ unsigned short f2bf(float v) {
    unsigned u = __float_as_uint(v);
    return (unsigned short)((u + 0x7FFFu + ((u >> 16) & 1)) >> 16);
}
__device__ __forceinline__ float bf2f(unsigned short h) {
    return __uint_as_float((unsigned)h << 16);
}

__device__ __forceinline__ int refl512(int t) {
    if (t < 0) t = -t;
    if (t > 511) t = 1022 - t;
    return t;
}

// ---------------------------------------------------------------- dark channel (fused min-c + row-min)
__global__ __launch_bounds__(256) void k_mrow(const float* __restrict__ x, float* __restrict__ tmp,
                                              int* __restrict__ gmax) {
    __shared__ float row[512];
    int i = blockIdx.x, tid = threadIdx.x;
    if (i == 0 && tid == 0) gmax[0] = 0;
    #pragma unroll
    for (int h = 0; h < 2; h++) {
        int j = tid + h * 256;
        int p = (i << 9) + j;
        float m = fmaxf(x[p], fmaxf(x[p + NPIX], x[p + 2 * NPIX]));
        row[j] = 1.0f - m;
    }
    __syncthreads();
    #pragma unroll
    for (int h = 0; h < 2; h++) {
        int j = tid + h * 256;
        float m = 1e30f;
        #pragma unroll
        for (int d = -7; d <= 7; d++) m = fminf(m, row[refl512(j + d)]);
        tmp[(i << 9) + j] = m;
    }
}

__global__ __launch_bounds__(256) void k_mincol_max(const float* __restrict__ tmp, float* __restrict__ dark,
                                                    int* __restrict__ gmax) {
    int p = blockIdx.x * 256 + threadIdx.x;
    int i = p >> 9, j = p & 511;
    float m = 1e30f;
    #pragma unroll
    for (int d = -7; d <= 7; d++) m = fminf(m, tmp[(refl512(i + d) << 9) + j]);
    dark[p] = m;
    __shared__ float red[256];
    int tid = threadIdx.x;
    red[tid] = m;
    __syncthreads();
    for (int s = 128; s > 0; s >>= 1) {
        if (tid < s) red[tid] = fmaxf(red[tid], red[tid + s]);
        __syncthreads();
    }
    if (tid == 0) atomicMax(gmax, __float_as_int(red[0]));
}

// ---------------------------------------------------------------- prep helpers (device)
__device__ __forceinline__ void prep_one(const float* __restrict__ w, unsigned short* __restrict__ h,
                                         unsigned short* __restrict__ l, int N, int K, int cshift, int idx) {
    if (idx >= N * K) return;
    int n = idx / K, kord = idx - n * K;
    int ksrc = kord;
    if (cshift) {
        int dydx = kord >> cshift, c = kord & ((1 << cshift) - 1);
        ksrc = c * 4 + dydx;
    }
    float v = w[n * K + ksrc];
    unsigned short hb = f2bf(v);
    h[idx] = hb;
    if (l) l[idx] = f2bf(v - bf2f(hb));
}

// ---------------------------------------------------------------- prepA: weight rounding + DFT tables
__global__ __launch_bounds__(256) void k_prepA(
    const float* __restrict__ w_d2, unsigned short* __restrict__ d2h, unsigned short* __restrict__ d2l,
    const float* __restrict__ w_a1, unsigned short* __restrict__ a1h, unsigned short* __restrict__ a1l,
    const float* __restrict__ w_a2, unsigned short* __restrict__ a2h, unsigned short* __restrict__ a2l,
    const float* __restrict__ w_s1, unsigned short* __restrict__ s1h,
    unsigned short* __restrict__ BfH, unsigned short* __restrict__ BfL,
    unsigned short* __restrict__ BfcH, unsigned short* __restrict__ BfcL,
    unsigned short* __restrict__ BicH, unsigned short* __restrict__ BicL,
    unsigned short* __restrict__ BirH, unsigned short* __restrict__ BirL,
    float* __restrict__ zbias) {
    int b = blockIdx.x, tid = threadIdx.x;
    if (b < 512)       { prep_one(w_d2, d2h, d2l, 256, 512, 7, b * 256 + tid); return; }
    else if (b < 768)  { prep_one(w_a1, a1h, a1l, 256, 256, 0, (b - 512) * 256 + tid); return; }
    else if (b < 1024) { prep_one(w_a2, a2h, a2l, 256, 256, 0, (b - 768) * 256 + tid); return; }
    else if (b < 1280) { prep_one(w_s1, s1h, nullptr, 256, 256, 0, (b - 1024) * 256 + tid); return; }
    int idx = (b - 1280) * 256 + tid;
    if (idx < 256) zbias[idx] = 0.f;
    const float w0 = 2.f * PI_F / 128.f;
    float v;
    unsigned short *H, *L;
    int off;
    if (idx < 32768) {                     // Bf [256][128]
        int n = idx >> 7, k = idx & 127;
        int t = n & 127, r = (t * k) & 127;
        float s_, c_; sincosf(w0 * r, &s_, &c_);
        v = (n < 128) ? c_ : -s_;
        H = BfH; L = BfL; off = idx;
    } else if (idx < 98304) {              // Bfc [256][256]
        int i = idx - 32768;
        int n = i >> 8, j = i & 255;
        int t = n & 127, r = (t * (j & 127)) & 127;
        float s_, c_; sincosf(w0 * r, &s_, &c_);
        v = (n < 128) ? ((j < 128) ? c_ : s_) : ((j < 128) ? -s_ : c_);
        H = BfcH; L = BfcL; off = i;
    } else if (idx < 163840) {             // Bic [256][256]
        int i = idx - 98304;
        int n = i >> 8, j = i & 255;
        int t = n & 127, r = (t * (j & 127)) & 127;
        float s_, c_; sincosf(w0 * r, &s_, &c_);
        v = ((n < 128) ? ((j < 128) ? c_ : -s_) : ((j < 128) ? s_ : c_)) * (1.f / 128.f);
        H = BicH; L = BicL; off = i;
    } else if (idx < 184320) {             // Bir [128][160]
        int i = idx - 163840;
        int col = i / 160, j = i - col * 160;
        if (j == 0) v = 1.f / 128.f;
        else if (j < 64)  { int r = (j * col) & 127; float s_, c_; sincosf(w0 * r, &s_, &c_); v = 2.f * c_ / 128.f; }
        else if (j == 64) v = (col & 1) ? -1.f / 128.f : 1.f / 128.f;
        else if (j >= 66 && j <= 128) { int k = j - 65; int r = (k * col) & 127; float s_, c_; sincosf(w0 * r, &s_, &c_); v = -2.f * s_ / 128.f; }
        else v = 0.f;
        H = BirH; L = BirL; off = i;
    } else return;
    unsigned short hb = f2bf(v);
    H[off] = hb;
    L[off] = f2bf(v - bf2f(hb));
}

// ---------------------------------------------------------------- prepB: all small composes
__global__ __launch_bounds__(256) void k_prepB(
    const float* __restrict__ w_u3, const float* __restrict__ w_u4, float* __restrict__ Uf,
    const float* __restrict__ w_e1, const float* __restrict__ b_e1,
    const float* __restrict__ w_e2, const float* __restrict__ b_e2,
    const float* __restrict__ w_d1, const float* __restrict__ b_d1,
    unsigned short* __restrict__ d1ch, float* __restrict__ b1c,
    const float* __restrict__ b_u3, const float* __restrict__ b_u4, float* __restrict__ b43,
    const float* __restrict__ w2, const float* __restrict__ b2,
    const float* __restrict__ w3, const float* __restrict__ b3,
    const float* __restrict__ wu2, const float* __restrict__ bu2,
    const float* __restrict__ wu1, const float* __restrict__ bu1,
    float* __restrict__ Wc, float* __restrict__ bc,
    float* __restrict__ W21c, float* __restrict__ b21c) {
    int b = blockIdx.x, tid = threadIdx.x;
    if (b < 64) {
        int idx = b * 256 + tid;
        int n = idx >> 8, j = idx & 255;
        float s = 0.f;
        #pragma unroll 16
        for (int o = 0; o < 128; o++) s += w_u4[n * 128 + o] * w_u3[o * 256 + j];
        Uf[idx] = s;
    } else if (b < 80) {
        __shared__ float E[192];
        if (tid < 192) {
            int o = tid / 3, ci = tid - o * 3;
            float s = 0.f;
            #pragma unroll
            for (int r = 0; r < 8; r++) s += w_e2[o * 8 + r] * w_e1[r * 3 + ci];
            E[tid] = s;
        }
        __syncthreads();
        int idx = (b - 64) * 256 + tid;    // < 4096
        int n = idx >> 5, k = idx & 31;
        float s = 0.f;
        if (k < 12) {
            int dydx = k / 3, ci = k - dydx * 3;
            #pragma unroll 16
            for (int o = 0; o < 64; o++) s += w_d1[n * 256 + o * 4 + dydx] * E[o * 3 + ci];
        }
        d1ch[idx] = f2bf(s);
    } else if (b == 80) {
        __shared__ float f[64];
        if (tid < 64) {
            int o = tid;
            float s = b_e2[o];
            #pragma unroll
            for (int r = 0; r < 8; r++) s += w_e2[o * 8 + r] * b_e1[r];
            f[o] = s;
        }
        __syncthreads();
        if (tid < 128) {
            float s = b_d1[tid];
            #pragma unroll 8
            for (int o = 0; o < 64; o++) {
                float fo = f[o];
                #pragma unroll
                for (int dydx = 0; dydx < 4; dydx++) s += w_d1[tid * 256 + o * 4 + dydx] * fo;
            }
            b1c[tid] = s;
        }
    } else if (b == 81) {
        if (tid < 64) {
            float s = b_u4[tid];
            #pragma unroll 16
            for (int o = 0; o < 128; o++) s += w_u4[tid * 128 + o] * b_u3[o];
            b43[tid] = s;
        }
    } else {
        __shared__ float sWc[384], sW2c[384];
        if (tid < 128) {
            int j = tid;
            for (int r = 0; r < 3; r++) {
                float s = 0.f;
                #pragma unroll 16
                for (int o = 0; o < 64; o++) s += w3[r * 64 + o] * w2[o * 128 + j];
                sWc[r * 128 + j] = s;
                Wc[r * 128 + j] = s;
            }
            if (j < 3) {
                float s = b3[j];
                #pragma unroll 16
                for (int o = 0; o < 64; o++) s += w3[j * 64 + o] * b2[o];
                bc[j] = s;
            }
        }
        __syncthreads();
        if (tid < 128) {
            int j = tid;
            for (int r = 0; r < 3; r++) {
                float s = 0.f;
                #pragma unroll 16
                for (int o = 0; o < 64; o++) s += sWc[r * 128 + o] * wu2[o * 128 + j];
                sW2c[r * 128 + j] = s;
            }
        }
        __syncthreads();
        if (tid < 256) {
            int j = tid;
            for (int r = 0; r < 3; r++) {
                float s = 0.f;
                #pragma unroll 16
                for (int o = 0; o < 128; o++) s += sW2c[r * 128 + o] * wu1[o * 256 + j];
                W21c[r * 256 + j] = s;
            }
        }
        if (tid < 3) {
            float s = 0.f;
            #pragma unroll 16
            for (int o = 0; o < 128; o++) s += sW2c[tid * 128 + o] * bu1[o];
            #pragma unroll 16
            for (int o = 0; o < 64; o++)  s += sWc[tid * 128 + o] * bu2[o];
            b21c[tid] = s;
        }
    }
}

// ---------------------------------------------------------------- Wg = (u4·u3)·w_sp2 compose, b_g fold
__global__ __launch_bounds__(256) void k_prep2(const float* __restrict__ Uf, const float* __restrict__ wsp2,
                                               const float* __restrict__ bsp2, const float* __restrict__ b43,
                                               unsigned short* __restrict__ Wg, float* __restrict__ bgc) {
    __shared__ float u[256], red[256];
    int n = blockIdx.x, tid = threadIdx.x;
    u[tid] = Uf[n * 256 + tid];
    __syncthreads();
    float s = 0.f;
    #pragma unroll 16
    for (int o = 0; o < 256; o++) s += u[o] * wsp2[o * 256 + tid];
    Wg[n * 256 + tid] = f2bf(s);
    red[tid] = u[tid] * bsp2[tid];
    __syncthreads();
    for (int st = 128; st > 0; st >>= 1) {
        if (tid < st) red[tid] += red[tid + st];
        __syncthreads();
    }
    if (tid == 0) bgc[n] = b43[n] + red[0];
}

// ---------------------------------------------------------------- channels-first MFMA GEMM
template<int AMODE, int SPLIT, int LRELU, int TSTORE, int ABF16, int CBF16>
__global__ __launch_bounds__(256) void k_mmcf(const void* __restrict__ Asrc_,
                                              const unsigned short* __restrict__ Bh,
                                              const unsigned short* __restrict__ Bl,
                                              const float* __restrict__ bias, void* __restrict__ C_,
                                              int M, int N, int K, int cshift, int wshift, int srcW,
                                              int gy) {
    const float* Af = (const float*)Asrc_;
    const unsigned short* A16 = (const unsigned short*)Asrc_;
    float* Cf = (float*)C_;
    unsigned short* C16 = (unsigned short*)C_;
    __shared__ unsigned short AhS[128 * 40];
    __shared__ unsigned short BhS[64 * 40];
    __shared__ unsigned short AlS[SPLIT ? 128 * 40 : 8];
    __shared__ unsigned short BlS[SPLIT ? 64 * 40 : 8];
    int tid = threadIdx.x;
    int nwg = (int)gridDim.x;
    int bid = blockIdx.x;
    int qq = nwg >> 3, rr = nwg & 7;
    int xcd = bid & 7, ixw = bid >> 3;
    int work = (xcd < rr) ? (xcd * (qq + 1) + ixw) : (rr * (qq + 1) + (xcd - rr) * qq + ixw);
    int bx = work / gy;
    int by = work - bx * gy;
    int m0 = bx * 128;
    int n0 = by * 64;
    int wave = tid >> 6, lane = tid & 63;
    int wm = (wave >> 1) * 64, wn = (wave & 1) * 32;
    int l15 = lane & 15, quad = lane >> 4;
    int lk = quad * 8, lk4 = quad * 4;
    fx4 acc[4][2];
    #pragma unroll
    for (int a = 0; a < 4; a++)
        #pragma unroll
        for (int b = 0; b < 2; b++)
            acc[a][b] = (fx4){0.f, 0.f, 0.f, 0.f};

    int mm = tid & 127;
    int kpb = tid >> 7;
    int gm = m0 + mm;
    int oj = 0, oi = 0, cA = 0, kfA = 0, tauA = 0;
    size_t abase = 0;
    if (AMODE == 1) { oj = gm & ((1 << wshift) - 1); oi = gm >> wshift; }
    if (AMODE == 2) { oj = gm & 255; oi = gm >> 8; }
    if (AMODE == 3) abase = (size_t)gm * K;
    if (AMODE == 7) { cA = gm / 65; kfA = gm - cA * 65; }
    if (AMODE == 8) { cA = gm >> 7; tauA = gm & 127; }
    if (AMODE == 9) { cA = gm / 65; kfA = gm - cA * 65; }

    for (int kb = 0; kb < K; kb += 32) {
        if (AMODE == 3 && ABF16 && !SPLIT) {
            #pragma unroll
            for (int half = 0; half < 2; half++) {
                sh8 hv = *(const sh8*)(const void*)&A16[abase + kb + kpb * 16 + half * 8];
                *(sh8*)(void*)&AhS[mm * 40 + (kpb * 2 + half) * 8] = hv;
            }
        } else {
            #pragma unroll
            for (int half = 0; half < 2; half++) {
                sh8 hv, lv;
                #pragma unroll
                for (int tt = 0; tt < 4; tt++) {
                    int kp = kpb * 8 + half * 4 + tt;
                    int k0 = kb + kp * 2;
                    unsigned short h0, h1;
                    if (ABF16) {
                        size_t ad0, ad1;
                        if (AMODE == 0) {
                            ad0 = (size_t)k0 * M + gm;
                            ad1 = ad0 + M;
                        } else if (AMODE == 1) {
                            int c = k0 & ((1 << cshift) - 1);
                            int dydx = k0 >> cshift;
                            int dy = dydx >> 1, dx = dydx & 1;
                            size_t pix = (size_t)(2 * oi + dy) * srcW + (2 * oj + dx);
                            size_t plane = (size_t)srcW * srcW;
                            ad0 = (size_t)c * plane + pix;
                            ad1 = ad0 + plane;
                        } else if (AMODE == 3) {
                            ad0 = abase + k0;
                            ad1 = ad0 + 1;
                        } else if (AMODE == 7) {
                            int t0 = k0 & 127, hf = k0 >> 7;
                            ad0 = (size_t)(cA * 128 + t0) * 256 + hf * 128 + kfA;
                            ad1 = ad0 + 256;
                        } else {               // AMODE 8
                            int j0 = k0, j1 = k0 + 1;
                            int kf0 = (j0 < 65) ? j0 : ((j0 < 130) ? j0 - 65 : 0);
                            int hf0 = (j0 >= 65 && j0 < 130) ? 1 : 0;
                            int kf1 = (j1 < 65) ? j1 : ((j1 < 130) ? j1 - 65 : 0);
                            int hf1 = (j1 >= 65 && j1 < 130) ? 1 : 0;
                            ad0 = (size_t)(cA * 65 + kf0) * 256 + hf0 * 128 + tauA;
                            ad1 = (size_t)(cA * 65 + kf1) * 256 + hf1 * 128 + tauA;
                        }
                        h0 = A16[ad0];
                        h1 = A16[ad1];
                    } else {
                        float a0, a1;
                        if (AMODE == 2) {
                            if (k0 < 12) {
                                int d0 = k0 / 3, c0 = k0 - d0 * 3;
                                int k1 = k0 + 1;
                                int d1x = k1 / 3, c1 = k1 - d1x * 3;
                                a0 = Af[(size_t)c0 * NPIX + (size_t)(2 * oi + (d0 >> 1)) * 512 + 2 * oj + (d0 & 1)];
                                a1 = Af[(size_t)c1 * NPIX + (size_t)(2 * oi + (d1x >> 1)) * 512 + 2 * oj + (d1x & 1)];
                            } else { a0 = 0.f; a1 = 0.f; }
                        } else if (AMODE == 9) {
                            size_t ad = (size_t)cA * 16640 + (size_t)k0 * 65 + kfA;
                            float re0 = Af[ad], im0 = Af[ad + 2129920];
                            float re1 = Af[ad + 65], im1 = Af[ad + 65 + 2129920];
                            a0 = sqrtf(re0 * re0 + im0 * im0);
                            a1 = sqrtf(re1 * re1 + im1 * im1);
                        } else {
                            size_t ad0 = (size_t)k0 * M + gm;
                            a0 = Af[ad0];
                            a1 = Af[ad0 + M];
                        }
                        h0 = f2bf(a0);
                        h1 = f2bf(a1);
                        if (SPLIT) {
                            lv[tt * 2] = (short)f2bf(a0 - bf2f(h0));
                            lv[tt * 2 + 1] = (short)f2bf(a1 - bf2f(h1));
                        }
                    }
                    hv[tt * 2] = (short)h0;
                    hv[tt * 2 + 1] = (short)h1;
                }
                int coff = (kpb * 2 + half) * 8;
                *(sh8*)(void*)&AhS[mm * 40 + coff] = hv;
                if (SPLIT) *(sh8*)(void*)&AlS[mm * 40 + coff] = lv;
            }
        }
        {
            int n = tid >> 2, seg = tid & 3;
            size_t gb = (size_t)(n0 + n) * K + kb + seg * 8;
            *(sh8*)(void*)&BhS[n * 40 + seg * 8] = *(const sh8*)(const void*)&Bh[gb];
            if (SPLIT) *(sh8*)(void*)&BlS[n * 40 + seg * 8] = *(const sh8*)(const void*)&Bl[gb];
        }
        __syncthreads();
        sh8 af[4], bf[2], afl[4], bfl[2];
        #pragma unroll
        for (int mt = 0; mt < 4; mt++) {
            af[mt] = *(const sh8*)(const void*)&AhS[(wm + mt * 16 + l15) * 40 + lk];
            if (SPLIT) afl[mt] = *(const sh8*)(const void*)&AlS[(wm + mt * 16 + l15) * 40 + lk];
        }
        #pragma unroll
        for (int nt = 0; nt < 2; nt++) {
            bf[nt] = *(const sh8*)(const void*)&BhS[(wn + nt * 16 + l15) * 40 + lk];
            if (SPLIT) bfl[nt] = *(const sh8*)(const void*)&BlS[(wn + nt * 16 + l15) * 40 + lk];
        }
        #pragma unroll
        for (int mt = 0; mt < 4; mt++)
            #pragma unroll
            for (int nt = 0; nt < 2; nt++) {
                acc[mt][nt] = __builtin_amdgcn_mfma_f32_16x16x32_bf16(af[mt], bf[nt], acc[mt][nt], 0, 0, 0);
                if (SPLIT) {
                    acc[mt][nt] = __builtin_amdgcn_mfma_f32_16x16x32_bf16(af[mt], bfl[nt], acc[mt][nt], 0, 0, 0);
                    acc[mt][nt] = __builtin_amdgcn_mfma_f32_16x16x32_bf16(afl[mt], bf[nt], acc[mt][nt], 0, 0, 0);
                }
            }
        __syncthreads();
    }
    #pragma unroll
    for (int nt = 0; nt < 2; nt++) {
        int n = n0 + wn + nt * 16 + l15;
        float bs = bias[n];
        #pragma unroll
        for (int mt = 0; mt < 4; mt++) {
            int mbase = m0 + wm + mt * 16 + lk4;
            if (TSTORE) {
                #pragma unroll
                for (int r = 0; r < 4; r++) {
                    float q = acc[mt][nt][r] + bs;
                    if (LRELU) q = (q < 0.f) ? 0.1f * q : q;
                    if (CBF16) C16[(size_t)(mbase + r) * N + n] = f2bf(q);
                    else       Cf[(size_t)(mbase + r) * N + n] = q;
                }
            } else if (CBF16) {
                ush4 v;
                #pragma unroll
                for (int r = 0; r < 4; r++) {
                    float q = acc[mt][nt][r] + bs;
                    if (LRELU) q = (q < 0.f) ? 0.1f * q : q;
                    v[r] = f2bf(q);
                }
                *(ush4*)(void*)&C16[(size_t)n * M + mbase] = v;
            } else {
                float4 v;
                float* vp = (float*)&v;
                #pragma unroll
                for (int r = 0; r < 4; r++) {
                    float q = acc[mt][nt][r] + bs;
                    if (LRELU) q = (q < 0.f) ? 0.1f * q : q;
                    vp[r] = q;
                }
                *(float4*)&Cf[(size_t)n * M + mbase] = v;
            }
        }
    }
}

// ---------------------------------------------------------------- z = a*(cos a, sin a), flattened full-wave, bf16
__global__ __launch_bounds__(256) void k_zbuild(const float* __restrict__ A2, unsigned short* __restrict__ Z) {
    int idx = blockIdx.x * 256 + threadIdx.x;   // < 2129920
    int ct = idx / 65, kf = idx - ct * 65;
    int c = ct >> 7, t = ct & 127;
    float a = A2[idx];
    float s_, c_;
    sincosf(a, &s_, &c_);
    size_t m = (size_t)c * 65 + kf;
    Z[(size_t)t * 16640 + m] = f2bf(a * c_);
    Z[2129920 + (size_t)t * 16640 + m] = f2bf(a * s_);
}

// ---------------------------------------------------------------- h3s = W21c @ I2T + b21c  (3ch @128^2, K=256)
__global__ __launch_bounds__(64) void k_h3s(const float* __restrict__ I2T, const float* __restrict__ W21c,
                                            const float* __restrict__ b21c, float* __restrict__ h3s) {
    __shared__ float wa[768], bs[3];
    int tid = threadIdx.x;
    for (int i = tid; i < 768; i += 64) wa[i] = W21c[i];
    if (tid < 3) bs[tid] = b21c[tid];
    __syncthreads();
    int q = blockIdx.x * 64 + tid;
    float a0 = bs[0], a1 = bs[1], a2 = bs[2];
    #pragma unroll 4
    for (int c = 0; c < 256; c++) {
        float v = I2T[(size_t)c * 16384 + q];
        a0 += wa[c] * v;
        a1 += wa[256 + c] * v;
        a2 += wa[512 + c] * v;
    }
    h3s[q] = a0; h3s[16384 + q] = a1; h3s[32768 + q] = a2;
}

// ---------------------------------------------------------------- final fused stage @512^2
// Block = one (row i, half-row j0). Double-bilinear taps: y-interp precomputed
// cooperatively into LDS (wy weights are block-uniform), then 3 LDS reads/channel.
__global__ __launch_bounds__(256) void k_final(const float* __restrict__ x,
                                               const float* __restrict__ dark, const int* __restrict__ gmax,
                                               const float* __restrict__ wcf1, const float* __restrict__ bcf1,
                                               const float* __restrict__ Wc, const float* __restrict__ bc,
                                               const float* __restrict__ g4s, const float* __restrict__ h3s,
                                               float* __restrict__ out) {
    __shared__ float idimt[32], w1[192], b1[64], wb[192], bcs[3], posy[16];
    __shared__ float gyr[64][68];   // y-interp g4s, 66 cols used (pad 68)
    __shared__ float hyr[3][68];    // y-interp h3s
    int tid = threadIdx.x;
    int bid = blockIdx.x;
    int i = bid >> 1;
    int j0 = (bid & 1) << 8;
    int j = j0 + tid;
    int p = (i << 9) + j;

    const float scale = 2.f * PI_F;
    float inv511 = scale / (511.f + 1e-6f);
    float ye = (float)i * inv511;

    if (tid < 32) idimt[tid] = 1.f / powf(10000.f, (float)(2 * (tid >> 1)) / 32.f);
    if (tid < 192) w1[tid] = wcf1[tid];
    if (tid < 64) b1[tid] = bcf1[tid];
    if (tid < 192) { int r = tid / 64, c = tid - (tid / 64) * 64; wb[tid] = Wc[r * 128 + 64 + c]; }
    if (tid < 3) bcs[tid] = bc[tid];
    __syncthreads();
    if (tid >= 32 && tid < 48) {
        int c = tid - 32;                 // channel 16+c
        float e = ye * idimt[c];
        posy[c] = ((c & 1) == 0) ? __sinf(e) : __cosf(e);
    }

    // block-uniform y taps/weights (512->128 composite)
    int ky = i >> 2, ry = i & 3;
    int ym = (ky > 0) ? ky - 1 : 0, yp = (ky < 127) ? ky + 1 : 127;
    float wy0 = (ry == 0) ? .375f : (ry == 1) ? .1875f : (ry == 2) ? .0625f : 0.f;
    float wy1 = (ry == 0 || ry == 3) ? .625f : .75f;
    float wy2 = (ry == 0) ? 0.f : (ry == 1) ? .0625f : (ry == 2) ? .1875f : .375f;
    int base = j0 >> 2;                   // 0 or 64
    int r0 = ym * 128, r1 = ky * 128, r2 = yp * 128;
    for (int idx = tid; idx < 64 * 66; idx += 256) {
        int c = idx / 66, t = idx - c * 66;
        int col = base - 1 + t;
        col = (col < 0) ? 0 : (col > 127) ? 127 : col;
        const float* gp = g4s + (size_t)c * 16384;
        gyr[c][t] = wy0 * gp[r0 + col] + wy1 * gp[r1 + col] + wy2 * gp[r2 + col];
    }
    for (int idx = tid; idx < 3 * 66; idx += 256) {
        int c = idx / 66, t = idx - c * 66;
        int col = base - 1 + t;
        col = (col < 0) ? 0 : (col > 127) ? 127 : col;
        const float* hp = h3s + (size_t)c * 16384;
        hyr[c][t] = wy0 * hp[r0 + col] + wy1 * hp[r1 + col] + wy2 * hp[r2 + col];
    }
    __syncthreads();

    float xe = (float)j * inv511;
    float gm = __int_as_float(gmax[0]);
    float ze = dark[p] / (gm + 1e-6f) * scale;
    float x0 = x[p], x1 = x[p + NPIX], x2 = x[p + 2 * NPIX];

    // x taps/weights
    int rx = j & 3;
    int tx = tid >> 2;                    // kx - base
    float wx0 = (rx == 0) ? .375f : (rx == 1) ? .1875f : (rx == 2) ? .0625f : 0.f;
    float wx1 = (rx == 0 || rx == 3) ? .625f : .75f;
    float wx2 = (rx == 0) ? 0.f : (rx == 1) ? .0625f : (rx == 2) ? .1875f : .375f;

    float a0 = 0.f, a1 = 0.f, a2 = 0.f;
    #pragma unroll 1
    for (int c = 0; c < 64; c++) {
        float pos;
        if (c < 16)      { float e = xe * idimt[c];      pos = ((c & 1) == 0) ? __sinf(e) : __cosf(e); }
        else if (c < 32) { pos = posy[c - 16]; }
        else             { float e = ze * idimt[c - 32]; pos = ((c & 1) == 0) ? __sinf(e) : __cosf(e); }
        float ape = pos + w1[c * 3] * x0 + w1[c * 3 + 1] * x1 + w1[c * 3 + 2] * x2 + b1[c];
        float gv = wx0 * gyr[c][tx] + wx1 * gyr[c][tx + 1] + wx2 * gyr[c][tx + 2];
        float s = gv * ape;
        a0 += wb[c] * s; a1 += wb[64 + c] * s; a2 += wb[128 + c] * s;
    }
    float f0 = wx0 * hyr[0][tx] + wx1 * hyr[0][tx + 1] + wx2 * hyr[0][tx + 2];
    float f1 = wx0 * hyr[1][tx] + wx1 * hyr[1][tx + 1] + wx2 * hyr[1][tx + 2];
    float f2 = wx0 * hyr[2][tx] + wx1 * hyr[2][tx + 1] + wx2 * hyr[2][tx + 2];
    out[p]            = a0 + f0 + bcs[0] + x0;
    out[NPIX + p]     = a1 + f1 + bcs[1] + x1;
    out[2 * NPIX + p] = a2 + f2 + bcs[2] + x2;
}

// ================================================================ launcher
extern "C" void kernel_launch(void* const* d_in, const int* in_sizes, int n_in,
                              void* d_out, int out_size, void* d_ws, size_t ws_size,
                              hipStream_t stream) {
    const float* x      = (const float*)d_in[0];
    const float* w_cf1  = (const float*)d_in[1];  const float* b_cf1 = (const float*)d_in[2];
    const float* w_e1   = (const float*)d_in[3];  const float* b_e1  = (const float*)d_in[4];
    const float* w_e2   = (const float*)d_in[5];  const float* b_e2  = (const float*)d_in[6];
    const float* w_d1   = (const float*)d_in[7];  const float* b_d1  = (const float*)d_in[8];
    const float* w_d2   = (const float*)d_in[9];  const float* b_d2  = (const float*)d_in[10];
    // 11..14: pha branch is dead code in the reference
    const float* w_amp1 = (const float*)d_in[15]; const float* b_amp1 = (const float*)d_in[16];
    const float* w_amp2 = (const float*)d_in[17]; const float* b_amp2 = (const float*)d_in[18];
    const float* w_sp1  = (const float*)d_in[19]; const float* b_sp1  = (const float*)d_in[20];
    const float* w_sp2  = (const float*)d_in[21]; const float* b_sp2  = (const float*)d_in[22];
    const float* w_u1   = (const float*)d_in[23]; const float* b_u1   = (const float*)d_in[24];
    const float* w_u2   = (const float*)d_in[25]; const float* b_u2   = (const float*)d_in[26];
    const float* w_u3   = (const float*)d_in[27]; const float* b_u3   = (const float*)d_in[28];
    const float* w_u4   = (const float*)d_in[29]; const float* b_u4   = (const float*)d_in[30];
    const float* w_cf2  = (const float*)d_in[31]; const float* b_cf2  = (const float*)d_in[32];
    const float* w_cf3  = (const float*)d_in[33]; const float* b_cf3  = (const float*)d_in[34];
    float* out = (float*)d_out;

    char* ws = (char*)d_ws;
    constexpr size_t MiB = 1ull << 20;
    float*  dark   = (float*)(ws + 0 * MiB);
    float*  tmp    = (float*)(ws + 1 * MiB);
    int*    gmax   = (int*)  (ws + 2 * MiB);
    float*  Wc     = (float*)(ws + 2 * MiB + 1024);
    float*  bc     = (float*)(ws + 2 * MiB + 2560);
    float*  W21c   = (float*)(ws + 2 * MiB + 4096);
    float*  b21c   = (float*)(ws + 2 * MiB + 7168);
    float*  b43    = (float*)(ws + 2 * MiB + 7424);
    unsigned short* d1ch = (unsigned short*)(ws + 3 * MiB);       // bf16 [128][32]
    float*  b1c    = (float*)(ws + 3 * MiB + 16384);
    float*  Uf     = (float*)(ws + 3 * MiB + 32768);              // fp32 [64][256]
    unsigned short* Wg = (unsigned short*)(ws + 3 * MiB + 131072);// bf16 [64][256]
    float*  bgc    = (float*)(ws + 3 * MiB + 196608);
    unsigned short* xd1 = (unsigned short*)(ws + 67 * MiB);   // bf16 [128][65536] = 16 MiB
    unsigned short* xd2 = (unsigned short*)(ws + 99 * MiB);   // bf16 [256][16384] =  8 MiB
    unsigned short* F1T = (unsigned short*)(ws + 115 * MiB);  // bf16 [32768][256] = 16 MiB
    float*  F2C    = (float*)(ws + 147 * MiB);                // fp32 (feeds sqrt fused in amp1)
    float*  A1     = (float*)(ws + 173 * MiB);
    float*  A2     = (float*)(ws + 182 * MiB);
    unsigned short* Zbuf = (unsigned short*)(ws + 115 * MiB); // bf16 (F1T dead after F2)
    unsigned short* I1T  = (unsigned short*)(ws + 132 * MiB); // bf16 [16640][256] = 8.5 MiB
    float*  I2T    = (float*)(ws + 149 * MiB);                // fp32 (feeds h3s fp32 dot)
    float*  h3s    = (float*)(ws + 11 * MiB);                 // fp32 [3][16384]
    unsigned short* s1 = (unsigned short*)(ws + 31 * MiB);    // bf16 [256][16384] = 8 MiB
    float*  g4s    = (float*)(ws + 87 * MiB);                 // fp32 [64][16384]
    unsigned short* wb16 = (unsigned short*)(ws + 192 * MiB);
    unsigned short* d2h = wb16 + 65536,   * d2l = wb16 + 196608;
    unsigned short* a1h = wb16 + 327680,  * a1l = wb16 + 393216;
    unsigned short* a2h = wb16 + 458752,  * a2l = wb16 + 524288;
    unsigned short* s1h = wb16 + 589824;
    unsigned short* BfH = wb16 + 786432,  * BfL = wb16 + 819200;
    unsigned short* BfcH = wb16 + 851968, * BfcL = wb16 + 917504;
    unsigned short* BicH = wb16 + 983040, * BicL = wb16 + 1048576;
    unsigned short* BirH = wb16 + 1114112,* BirL = wb16 + 1134592;
    float* zbias = (float*)(ws + 195 * MiB + 512 * 1024);

    // 1) dark channel + gmax ; merged prep (3 launches)
    k_mrow<<<512, 256, 0, stream>>>(x, tmp, gmax);
    k_mincol_max<<<1024, 256, 0, stream>>>(tmp, dark, gmax);
    k_prepA<<<2000, 256, 0, stream>>>(w_d2, d2h, d2l, w_amp1, a1h, a1l, w_amp2, a2h, a2l, w_sp1, s1h,
                                      BfH, BfL, BfcH, BfcL, BicH, BicL, BirH, BirL, zbias);
    k_prepB<<<83, 256, 0, stream>>>(w_u3, w_u4, Uf,
                                    w_e1, b_e1, w_e2, b_e2, w_d1, b_d1, d1ch, b1c,
                                    b_u3, b_u4, b43,
                                    w_cf2, b_cf2, w_cf3, b_cf3, w_u2, b_u2, w_u1, b_u1,
                                    Wc, bc, W21c, b21c);
    k_prep2<<<64, 256, 0, stream>>>(Uf, w_sp2, b_sp2, b43, Wg, bgc);

    // 2) composed d1 = (w_d1∘w_e2∘w_e1) on 2x2 x-patches, K=12→32 ; d2
    k_mmcf<2, 0, 0, 0, 0, 1><<<1024, 256, 0, stream>>>(x, d1ch, nullptr, b1c, xd1, 65536, 128, 32, 0, 0, 0, 2);
    k_mmcf<1, 0, 0, 0, 1, 1><<<512, 256, 0, stream>>>(xd1, d2h, nullptr, b_d2, xd2, 16384, 256, 512, 7, 7, 256, 4);

    // 3) FFT section (amp = sqrt fused into amp1 A-stage)
    k_mmcf<3, 0, 0, 1, 1, 1><<<1024, 256, 0, stream>>>(xd2, BfH, nullptr, zbias, F1T, 32768, 256, 128, 0, 0, 0, 4);
    k_mmcf<7, 0, 0, 0, 1, 0><<<520, 256, 0, stream>>>(F1T, BfcH, nullptr, zbias, F2C, 16640, 256, 256, 0, 0, 0, 4);
    k_mmcf<9, 1, 1, 0, 0, 0><<<260, 256, 0, stream>>>(F2C, a1h, a1l, b_amp1, A1, 8320, 256, 256, 0, 0, 0, 4);
    k_mmcf<0, 1, 0, 0, 0, 0><<<260, 256, 0, stream>>>(A1, a2h, a2l, b_amp2, A2, 8320, 256, 256, 0, 0, 0, 4);
    k_zbuild<<<8320, 256, 0, stream>>>(A2, Zbuf);
    k_mmcf<0, 0, 0, 1, 1, 1><<<520, 256, 0, stream>>>(Zbuf, BicH, nullptr, zbias, I1T, 16640, 256, 256, 0, 0, 0, 4);
    k_mmcf<8, 0, 0, 1, 1, 0><<<512, 256, 0, stream>>>(I1T, BirH, nullptr, zbias, I2T, 32768, 128, 160, 0, 0, 0, 2);

    // 4) four path: h3s = W21c @ I2T (@128^2; upsample folded into k_final)
    k_h3s<<<256, 64, 0, stream>>>(I2T, W21c, b21c, h3s);

    // 5) spat path: sp1 ; composed (u4·u3·sp2) GEMM (@128^2; upsample folded into k_final)
    k_mmcf<0, 0, 1, 0, 1, 1><<<512, 256, 0, stream>>>(xd2, s1h, nullptr, b_sp1, s1, 16384, 256, 256, 0, 0, 0, 4);
    k_mmcf<0, 0, 0, 0, 1, 0><<<128, 256, 0, stream>>>(s1, Wg, nullptr, bgc, g4s, 16384, 64, 256, 0, 0, 0, 1);

    // 6) final fused stage (y-interp staged in LDS)
    k_final<<<1024, 256, 0, stream>>>(x, dark, gmax, w_cf1, b_cf1, Wc, bc, g4s, h3s, out);
}

// Round 7
// 345.033 us; speedup vs baseline: 1.1305x; 1.0342x over previous
//
#include <hip/hip_runtime.h>
#include <math.h>

#define PI_F 3.14159265358979323846f
#define NPIX 262144   // 512*512

typedef __attribute__((ext_vector_type(8))) short sh8;
typedef __attribute__((ext_vector_type(4))) float fx4;
typedef __attribute__((ext_vector_type(4))) unsigned short ush4;

__device__ __forceinline__ unsigned short f2bf(float v) {
    unsigned u = __float_as_uint(v);
    return (unsigned short)((u + 0x7FFFu + ((u >> 16) & 1)) >> 16);
}
__device__ __forceinline__ float bf2f(unsigned short h) {
    return __uint_as_float((unsigned)h << 16);
}

__device__ __forceinline__ int refl512(int t) {
    if (t < 0) t = -t;
    if (t > 511) t = 1022 - t;
    return t;
}

// ---------------------------------------------------------------- fused dark channel (min-c + row-min + col-min + gmax)
// block = output row i; 15 needed row-mins recomputed in LDS (cheap), tmp round-trip deleted.
// gmax[0] is zeroed by k_prepA (launched before).
__global__ __launch_bounds__(256) void k_dark(const float* __restrict__ x, float* __restrict__ dark,
                                              int* __restrict__ gmax) {
    __shared__ float rm[15][512];
    __shared__ float hm[15][512];
    __shared__ float red[256];
    int i = blockIdx.x, tid = threadIdx.x;
    for (int idx = tid; idx < 15 * 512; idx += 256) {
        int rr = idx >> 9, j = idx & 511;
        int row = refl512(i - 7 + rr);
        int p = (row << 9) + j;
        rm[rr][j] = 1.0f - fmaxf(x[p], fmaxf(x[p + NPIX], x[p + 2 * NPIX]));
    }
    __syncthreads();
    for (int idx = tid; idx < 15 * 512; idx += 256) {
        int rr = idx >> 9, j = idx & 511;
        float m = 1e30f;
        #pragma unroll
        for (int d = -7; d <= 7; d++) m = fminf(m, rm[rr][refl512(j + d)]);
        hm[rr][j] = m;
    }
    __syncthreads();
    float best = -1e30f;
    #pragma unroll
    for (int h = 0; h < 2; h++) {
        int j = tid + h * 256;
        float m = 1e30f;
        #pragma unroll
        for (int rr = 0; rr < 15; rr++) m = fminf(m, hm[rr][j]);
        dark[(i << 9) + j] = m;
        best = fmaxf(best, m);
    }
    red[tid] = best;
    __syncthreads();
    for (int s = 128; s > 0; s >>= 1) {
        if (tid < s) red[tid] = fmaxf(red[tid], red[tid + s]);
        __syncthreads();
    }
    if (tid == 0) atomicMax(gmax, __float_as_int(red[0]));
}

// ---------------------------------------------------------------- prep helpers (device)
__device__ __forceinline__ void prep_one(const float* __restrict__ w, unsigned short* __restrict__ h,
                                         unsigned short* __restrict__ l, int N, int K, int cshift, int idx) {
    if (idx >= N * K) return;
    int n = idx / K, kord = idx - n * K;
    int ksrc = kord;
    if (cshift) {
        int dydx = kord >> cshift, c = kord & ((1 << cshift) - 1);
        ksrc = c * 4 + dydx;
    }
    float v = w[n * K + ksrc];
    unsigned short hb = f2bf(v);
    h[idx] = hb;
    if (l) l[idx] = f2bf(v - bf2f(hb));
}

// ---------------------------------------------------------------- prepA: weight rounding + DFT tables + Uf + Birf + gmax zero
__global__ __launch_bounds__(256) void k_prepA(
    const float* __restrict__ w_d2, unsigned short* __restrict__ d2h, unsigned short* __restrict__ d2l,
    const float* __restrict__ w_a1, unsigned short* __restrict__ a1h, unsigned short* __restrict__ a1l,
    const float* __restrict__ w_a2, unsigned short* __restrict__ a2h, unsigned short* __restrict__ a2l,
    const float* __restrict__ w_s1, unsigned short* __restrict__ s1h,
    const float* __restrict__ w_u3, const float* __restrict__ w_u4, float* __restrict__ Uf,
    unsigned short* __restrict__ BfH, unsigned short* __restrict__ BfL,
    unsigned short* __restrict__ BfcH, unsigned short* __restrict__ BfcL,
    unsigned short* __restrict__ BicH, unsigned short* __restrict__ BicL,
    float* __restrict__ Birf,
    float* __restrict__ zbias, int* __restrict__ gmax) {
    int b = blockIdx.x, tid = threadIdx.x;
    if (b == 0 && tid == 0) gmax[0] = 0;
    if (b < 512)       { prep_one(w_d2, d2h, d2l, 256, 512, 7, b * 256 + tid); return; }
    else if (b < 768)  { prep_one(w_a1, a1h, a1l, 256, 256, 0, (b - 512) * 256 + tid); return; }
    else if (b < 1024) { prep_one(w_a2, a2h, a2l, 256, 256, 0, (b - 768) * 256 + tid); return; }
    else if (b < 1280) { prep_one(w_s1, s1h, nullptr, 256, 256, 0, (b - 1024) * 256 + tid); return; }
    else if (b >= 2000) {                  // Uf = w_u4 · w_u3 (fp32)
        int idx = (b - 2000) * 256 + tid;
        int n = idx >> 8, j = idx & 255;
        float s = 0.f;
        #pragma unroll 16
        for (int o = 0; o < 128; o++) s += w_u4[n * 128 + o] * w_u3[o * 256 + j];
        Uf[idx] = s;
        return;
    }
    int idx = (b - 1280) * 256 + tid;
    if (idx < 256) zbias[idx] = 0.f;
    const float w0 = 2.f * PI_F / 128.f;
    float v;
    unsigned short *H, *L;
    int off;
    if (idx < 32768) {                     // Bf [256][128]
        int n = idx >> 7, k = idx & 127;
        int t = n & 127, r = (t * k) & 127;
        float s_, c_; sincosf(w0 * r, &s_, &c_);
        v = (n < 128) ? c_ : -s_;
        H = BfH; L = BfL; off = idx;
    } else if (idx < 98304) {              // Bfc [256][256]
        int i = idx - 32768;
        int n = i >> 8, j = i & 255;
        int t = n & 127, r = (t * (j & 127)) & 127;
        float s_, c_; sincosf(w0 * r, &s_, &c_);
        v = (n < 128) ? ((j < 128) ? c_ : s_) : ((j < 128) ? -s_ : c_);
        H = BfcH; L = BfcL; off = i;
    } else if (idx < 163840) {             // Bic [256][256]
        int i = idx - 98304;
        int n = i >> 8, j = i & 255;
        int t = n & 127, r = (t * (j & 127)) & 127;
        float s_, c_; sincosf(w0 * r, &s_, &c_);
        v = ((n < 128) ? ((j < 128) ? c_ : -s_) : ((j < 128) ? s_ : c_)) * (1.f / 128.f);
        H = BicH; L = BicL; off = i;
    } else if (idx < 184320) {             // Birf [160][128] fp32 (lane-coalesced layout)
        int i2 = idx - 163840;
        int col = i2 / 160, j = i2 - col * 160;
        if (j == 0) v = 1.f / 128.f;
        else if (j < 64)  { int r = (j * col) & 127; float s_, c_; sincosf(w0 * r, &s_, &c_); v = 2.f * c_ / 128.f; }
        else if (j == 64) v = (col & 1) ? -1.f / 128.f : 1.f / 128.f;
        else if (j >= 66 && j <= 128) { int k = j - 65; int r = (k * col) & 127; float s_, c_; sincosf(w0 * r, &s_, &c_); v = -2.f * s_ / 128.f; }
        else v = 0.f;
        Birf[j * 128 + col] = v;
        return;
    } else return;
    unsigned short hb = f2bf(v);
    H[off] = hb;
    L[off] = f2bf(v - bf2f(hb));
}

// ---------------------------------------------------------------- prepB: small composes + Wg/bgc (prep2 merged)
__global__ __launch_bounds__(256) void k_prepB(
    const float* __restrict__ Uf,
    const float* __restrict__ w_e1, const float* __restrict__ b_e1,
    const float* __restrict__ w_e2, const float* __restrict__ b_e2,
    const float* __restrict__ w_d1, const float* __restrict__ b_d1,
    unsigned short* __restrict__ d1ch, float* __restrict__ b1c,
    const float* __restrict__ w_u4, const float* __restrict__ b_u3, const float* __restrict__ b_u4,
    const float* __restrict__ wsp2, const float* __restrict__ bsp2,
    unsigned short* __restrict__ Wg, float* __restrict__ bgc,
    const float* __restrict__ w2, const float* __restrict__ b2,
    const float* __restrict__ w3, const float* __restrict__ b3,
    const float* __restrict__ wu2, const float* __restrict__ bu2,
    const float* __restrict__ wu1, const float* __restrict__ bu1,
    float* __restrict__ Wc, float* __restrict__ bc,
    float* __restrict__ W21c, float* __restrict__ b21c) {
    int b = blockIdx.x, tid = threadIdx.x;
    if (b < 16) {
        __shared__ float E[192];
        if (tid < 192) {
            int o = tid / 3, ci = tid - o * 3;
            float s = 0.f;
            #pragma unroll
            for (int r = 0; r < 8; r++) s += w_e2[o * 8 + r] * w_e1[r * 3 + ci];
            E[tid] = s;
        }
        __syncthreads();
        int idx = b * 256 + tid;           // < 4096
        int n = idx >> 5, k = idx & 31;
        float s = 0.f;
        if (k < 12) {
            int dydx = k / 3, ci = k - dydx * 3;
            #pragma unroll 16
            for (int o = 0; o < 64; o++) s += w_d1[n * 256 + o * 4 + dydx] * E[o * 3 + ci];
        }
        d1ch[idx] = f2bf(s);
    } else if (b == 16) {
        __shared__ float f[64];
        if (tid < 64) {
            int o = tid;
            float s = b_e2[o];
            #pragma unroll
            for (int r = 0; r < 8; r++) s += w_e2[o * 8 + r] * b_e1[r];
            f[o] = s;
        }
        __syncthreads();
        if (tid < 128) {
            float s = b_d1[tid];
            #pragma unroll 8
            for (int o = 0; o < 64; o++) {
                float fo = f[o];
                #pragma unroll
                for (int dydx = 0; dydx < 4; dydx++) s += w_d1[tid * 256 + o * 4 + dydx] * fo;
            }
            b1c[tid] = s;
        }
    } else if (b == 17) {
        __shared__ float sWc[384], sW2c[384];
        if (tid < 128) {
            int j = tid;
            for (int r = 0; r < 3; r++) {
                float s = 0.f;
                #pragma unroll 16
                for (int o = 0; o < 64; o++) s += w3[r * 64 + o] * w2[o * 128 + j];
                sWc[r * 128 + j] = s;
                Wc[r * 128 + j] = s;
            }
            if (j < 3) {
                float s = b3[j];
                #pragma unroll 16
                for (int o = 0; o < 64; o++) s += w3[j * 64 + o] * b2[o];
                bc[j] = s;
            }
        }
        __syncthreads();
        if (tid < 128) {
            int j = tid;
            for (int r = 0; r < 3; r++) {
                float s = 0.f;
                #pragma unroll 16
                for (int o = 0; o < 64; o++) s += sWc[r * 128 + o] * wu2[o * 128 + j];
                sW2c[r * 128 + j] = s;
            }
        }
        __syncthreads();
        if (tid < 256) {
            int j = tid;
            for (int r = 0; r < 3; r++) {
                float s = 0.f;
                #pragma unroll 16
                for (int o = 0; o < 128; o++) s += sW2c[r * 128 + o] * wu1[o * 256 + j];
                W21c[r * 256 + j] = s;
            }
        }
        if (tid < 3) {
            float s = 0.f;
            #pragma unroll 16
            for (int o = 0; o < 128; o++) s += sW2c[tid * 128 + o] * bu1[o];
            #pragma unroll 16
            for (int o = 0; o < 64; o++)  s += sWc[tid * 128 + o] * bu2[o];
            b21c[tid] = s;
        }
    } else {                               // b in 18..81 : Wg = Uf · wsp2 ; bgc = b_u4 + w_u4·b_u3 + Uf·bsp2
        int n = b - 18;
        __shared__ float u[256], red[256];
        u[tid] = Uf[n * 256 + tid];
        __syncthreads();
        float s = 0.f;
        #pragma unroll 16
        for (int o = 0; o < 256; o++) s += u[o] * wsp2[o * 256 + tid];
        Wg[n * 256 + tid] = f2bf(s);
        float rv = u[tid] * bsp2[tid];
        if (tid < 128) rv += w_u4[n * 128 + tid] * b_u3[tid];
        red[tid] = rv;
        __syncthreads();
        for (int st = 128; st > 0; st >>= 1) {
            if (tid < st) red[tid] += red[tid + st];
            __syncthreads();
        }
        if (tid == 0) bgc[n] = b_u4[n] + red[0];
    }
}

// ---------------------------------------------------------------- channels-first MFMA GEMM
template<int AMODE, int SPLIT, int LRELU, int TSTORE, int ABF16, int CBF16>
__global__ __launch_bounds__(256) void k_mmcf(const void* __restrict__ Asrc_,
                                              const unsigned short* __restrict__ Bh,
                                              const unsigned short* __restrict__ Bl,
                                              const float* __restrict__ bias, void* __restrict__ C_,
                                              int M, int N, int K, int cshift, int wshift, int srcW,
                                              int gy) {
    const float* Af = (const float*)Asrc_;
    const unsigned short* A16 = (const unsigned short*)Asrc_;
    float* Cf = (float*)C_;
    unsigned short* C16 = (unsigned short*)C_;
    __shared__ unsigned short AhS[128 * 40];
    __shared__ unsigned short BhS[64 * 40];
    __shared__ unsigned short AlS[SPLIT ? 128 * 40 : 8];
    __shared__ unsigned short BlS[SPLIT ? 64 * 40 : 8];
    int tid = threadIdx.x;
    int nwg = (int)gridDim.x;
    int bid = blockIdx.x;
    int qq = nwg >> 3, rr = nwg & 7;
    int xcd = bid & 7, ixw = bid >> 3;
    int work = (xcd < rr) ? (xcd * (qq + 1) + ixw) : (rr * (qq + 1) + (xcd - rr) * qq + ixw);
    int bx = work / gy;
    int by = work - bx * gy;
    int m0 = bx * 128;
    int n0 = by * 64;
    int wave = tid >> 6, lane = tid & 63;
    int wm = (wave >> 1) * 64, wn = (wave & 1) * 32;
    int l15 = lane & 15, quad = lane >> 4;
    int lk = quad * 8, lk4 = quad * 4;
    fx4 acc[4][2];
    #pragma unroll
    for (int a = 0; a < 4; a++)
        #pragma unroll
        for (int b = 0; b < 2; b++)
            acc[a][b] = (fx4){0.f, 0.f, 0.f, 0.f};

    int mm = tid & 127;
    int kpb = tid >> 7;
    int gm = m0 + mm;
    int oj = 0, oi = 0, cA = 0, kfA = 0, tauA = 0;
    size_t abase = 0;
    if (AMODE == 1) { oj = gm & ((1 << wshift) - 1); oi = gm >> wshift; }
    if (AMODE == 2) { oj = gm & 255; oi = gm >> 8; }
    if (AMODE == 3) abase = (size_t)gm * K;
    if (AMODE == 7) { cA = gm / 65; kfA = gm - cA * 65; }
    if (AMODE == 9) { cA = gm / 65; kfA = gm - cA * 65; }

    for (int kb = 0; kb < K; kb += 32) {
        if (AMODE == 3 && ABF16 && !SPLIT) {
            #pragma unroll
            for (int half = 0; half < 2; half++) {
                sh8 hv = *(const sh8*)(const void*)&A16[abase + kb + kpb * 16 + half * 8];
                *(sh8*)(void*)&AhS[mm * 40 + (kpb * 2 + half) * 8] = hv;
            }
        } else {
            #pragma unroll
            for (int half = 0; half < 2; half++) {
                sh8 hv, lv;
                #pragma unroll
                for (int tt = 0; tt < 4; tt++) {
                    int kp = kpb * 8 + half * 4 + tt;
                    int k0 = kb + kp * 2;
                    unsigned short h0, h1;
                    if (ABF16) {
                        size_t ad0, ad1;
                        if (AMODE == 0) {
                            ad0 = (size_t)k0 * M + gm;
                            ad1 = ad0 + M;
                        } else if (AMODE == 1) {
                            int c = k0 & ((1 << cshift) - 1);
                            int dydx = k0 >> cshift;
                            int dy = dydx >> 1, dx = dydx & 1;
                            size_t pix = (size_t)(2 * oi + dy) * srcW + (2 * oj + dx);
                            size_t plane = (size_t)srcW * srcW;
                            ad0 = (size_t)c * plane + pix;
                            ad1 = ad0 + plane;
                        } else if (AMODE == 3) {
                            ad0 = abase + k0;
                            ad1 = ad0 + 1;
                        } else {               // AMODE 7
                            int t0 = k0 & 127, hf = k0 >> 7;
                            ad0 = (size_t)(cA * 128 + t0) * 256 + hf * 128 + kfA;
                            ad1 = ad0 + 256;
                        }
                        h0 = A16[ad0];
                        h1 = A16[ad1];
                    } else {
                        float a0, a1;
                        if (AMODE == 2) {
                            if (k0 < 12) {
                                int d0 = k0 / 3, c0 = k0 - d0 * 3;
                                int k1 = k0 + 1;
                                int d1x = k1 / 3, c1 = k1 - d1x * 3;
                                a0 = Af[(size_t)c0 * NPIX + (size_t)(2 * oi + (d0 >> 1)) * 512 + 2 * oj + (d0 & 1)];
                                a1 = Af[(size_t)c1 * NPIX + (size_t)(2 * oi + (d1x >> 1)) * 512 + 2 * oj + (d1x & 1)];
                            } else { a0 = 0.f; a1 = 0.f; }
                        } else if (AMODE == 9) {
                            size_t ad = (size_t)cA * 16640 + (size_t)k0 * 65 + kfA;
                            float re0 = Af[ad], im0 = Af[ad + 2129920];
                            float re1 = Af[ad + 65], im1 = Af[ad + 65 + 2129920];
                            a0 = sqrtf(re0 * re0 + im0 * im0);
                            a1 = sqrtf(re1 * re1 + im1 * im1);
                        } else {
                            size_t ad0 = (size_t)k0 * M + gm;
                            a0 = Af[ad0];
                            a1 = Af[ad0 + M];
                        }
                        h0 = f2bf(a0);
                        h1 = f2bf(a1);
                        if (SPLIT) {
                            lv[tt * 2] = (short)f2bf(a0 - bf2f(h0));
                            lv[tt * 2 + 1] = (short)f2bf(a1 - bf2f(h1));
                        }
                    }
                    hv[tt * 2] = (short)h0;
                    hv[tt * 2 + 1] = (short)h1;
                }
                int coff = (kpb * 2 + half) * 8;
                *(sh8*)(void*)&AhS[mm * 40 + coff] = hv;
                if (SPLIT) *(sh8*)(void*)&AlS[mm * 40 + coff] = lv;
            }
        }
        {
            int n = tid >> 2, seg = tid & 3;
            size_t gb = (size_t)(n0 + n) * K + kb + seg * 8;
            *(sh8*)(void*)&BhS[n * 40 + seg * 8] = *(const sh8*)(const void*)&Bh[gb];
            if (SPLIT) *(sh8*)(void*)&BlS[n * 40 + seg * 8] = *(const sh8*)(const void*)&Bl[gb];
        }
        __syncthreads();
        sh8 af[4], bf[2], afl[4], bfl[2];
        #pragma unroll
        for (int mt = 0; mt < 4; mt++) {
            af[mt] = *(const sh8*)(const void*)&AhS[(wm + mt * 16 + l15) * 40 + lk];
            if (SPLIT) afl[mt] = *(const sh8*)(const void*)&AlS[(wm + mt * 16 + l15) * 40 + lk];
        }
        #pragma unroll
        for (int nt = 0; nt < 2; nt++) {
            bf[nt] = *(const sh8*)(const void*)&BhS[(wn + nt * 16 + l15) * 40 + lk];
            if (SPLIT) bfl[nt] = *(const sh8*)(const void*)&BlS[(wn + nt * 16 + l15) * 40 + lk];
        }
        #pragma unroll
        for (int mt = 0; mt < 4; mt++)
            #pragma unroll
            for (int nt = 0; nt < 2; nt++) {
                acc[mt][nt] = __builtin_amdgcn_mfma_f32_16x16x32_bf16(af[mt], bf[nt], acc[mt][nt], 0, 0, 0);
                if (SPLIT) {
                    acc[mt][nt] = __builtin_amdgcn_mfma_f32_16x16x32_bf16(af[mt], bfl[nt], acc[mt][nt], 0, 0, 0);
                    acc[mt][nt] = __builtin_amdgcn_mfma_f32_16x16x32_bf16(afl[mt], bf[nt], acc[mt][nt], 0, 0, 0);
                }
            }
        __syncthreads();
    }
    #pragma unroll
    for (int nt = 0; nt < 2; nt++) {
        int n = n0 + wn + nt * 16 + l15;
        float bs = bias[n];
        #pragma unroll
        for (int mt = 0; mt < 4; mt++) {
            int mbase = m0 + wm + mt * 16 + lk4;
            if (TSTORE) {
                #pragma unroll
                for (int r = 0; r < 4; r++) {
                    float q = acc[mt][nt][r] + bs;
                    if (LRELU) q = (q < 0.f) ? 0.1f * q : q;
                    if (CBF16) C16[(size_t)(mbase + r) * N + n] = f2bf(q);
                    else       Cf[(size_t)(mbase + r) * N + n] = q;
                }
            } else if (CBF16) {
                ush4 v;
                #pragma unroll
                for (int r = 0; r < 4; r++) {
                    float q = acc[mt][nt][r] + bs;
                    if (LRELU) q = (q < 0.f) ? 0.1f * q : q;
                    v[r] = f2bf(q);
                }
                *(ush4*)(void*)&C16[(size_t)n * M + mbase] = v;
            } else {
                float4 v;
                float* vp = (float*)&v;
                #pragma unroll
                for (int r = 0; r < 4; r++) {
                    float q = acc[mt][nt][r] + bs;
                    if (LRELU) q = (q < 0.f) ? 0.1f * q : q;
                    vp[r] = q;
                }
                *(float4*)&Cf[(size_t)n * M + mbase] = v;
            }
        }
    }
}

// ---------------------------------------------------------------- z = a*(cos a, sin a), flattened full-wave, bf16
__global__ __launch_bounds__(256) void k_zbuild(const float* __restrict__ A2, unsigned short* __restrict__ Z) {
    int idx = blockIdx.x * 256 + threadIdx.x;   // < 2129920
    int ct = idx / 65, kf = idx - ct * 65;
    int c = ct >> 7, t = ct & 127;
    float a = A2[idx];
    float s_, c_;
    sincosf(a, &s_, &c_);
    size_t m = (size_t)c * 65 + kf;
    Z[(size_t)t * 16640 + m] = f2bf(a * c_);
    Z[2129920 + (size_t)t * 16640 + m] = f2bf(a * s_);
}

// ---------------------------------------------------------------- P[r][kf][ht] = sum_c W21c[r][c] * I1T[(c,kf)][ht]
__global__ __launch_bounds__(256) void k_pfold(const unsigned short* __restrict__ I1T,
                                               const float* __restrict__ W21c, float* __restrict__ P) {
    __shared__ float wa[768];
    int kf = blockIdx.x, tid = threadIdx.x;
    for (int t = tid; t < 768; t += 256) wa[t] = W21c[t];
    __syncthreads();
    float a0 = 0.f, a1 = 0.f, a2 = 0.f;
    #pragma unroll 4
    for (int c = 0; c < 256; c++) {
        float v = bf2f(I1T[(size_t)(c * 65 + kf) * 256 + tid]);
        a0 += wa[c] * v;
        a1 += wa[256 + c] * v;
        a2 += wa[512 + c] * v;
    }
    P[(size_t)(0 * 65 + kf) * 256 + tid] = a0;
    P[(size_t)(1 * 65 + kf) * 256 + tid] = a1;
    P[(size_t)(2 * 65 + kf) * 256 + tid] = a2;
}

// ---------------------------------------------------------------- h3s[r][tau][col] = sum_k Birf[k][col] * P[r][kf(k)][hf(k),tau] + b21c[r]
__global__ __launch_bounds__(128) void k_h3f(const float* __restrict__ P, const float* __restrict__ Birf,
                                             const float* __restrict__ b21c, float* __restrict__ h3s) {
    __shared__ float sp[390];   // [r][hf*65+kf]
    __shared__ float bs[3];
    int tau = blockIdx.x, col = threadIdx.x;
    for (int t = col; t < 390; t += 128) {
        int r = t / 130, rem = t - r * 130;
        int hf = rem / 65, kf = rem - hf * 65;
        sp[t] = P[(size_t)(r * 65 + kf) * 256 + hf * 128 + tau];
    }
    if (col < 3) bs[col] = b21c[col];
    __syncthreads();
    float f0 = 0.f, f1 = 0.f, f2 = 0.f;
    for (int k0 = 0; k0 < 130; k0++) {      // Birf[j] == 0 for j >= 129
        float w = Birf[k0 * 128 + col];
        int hf = (k0 >= 65) ? 1 : 0;
        int base = hf ? (65 + k0 - 65) : k0;   // hf*65 + kf
        f0 += w * sp[base];
        f1 += w * sp[130 + base];
        f2 += w * sp[260 + base];
    }
    size_t q = (size_t)tau * 128 + col;
    h3s[q]         = f0 + bs[0];
    h3s[16384 + q] = f1 + bs[1];
    h3s[32768 + q] = f2 + bs[2];
}

// ---------------------------------------------------------------- final fused stage @512^2 (y-interp staged in LDS)
__global__ __launch_bounds__(256) void k_final(const float* __restrict__ x,
                                               const float* __restrict__ dark, const int* __restrict__ gmax,
                                               const float* __restrict__ wcf1, const float* __restrict__ bcf1,
                                               const float* __restrict__ Wc, const float* __restrict__ bc,
                                               const float* __restrict__ g4s, const float* __restrict__ h3s,
                                               float* __restrict__ out) {
    __shared__ float idimt[32], w1[192], b1[64], wb[192], bcs[3], posy[16];
    __shared__ float gyr[64][68];
    __shared__ float hyr[3][68];
    int tid = threadIdx.x;
    int bid = blockIdx.x;
    int i = bid >> 1;
    int j0 = (bid & 1) << 8;
    int j = j0 + tid;
    int p = (i << 9) + j;

    const float scale = 2.f * PI_F;
    float inv511 = scale / (511.f + 1e-6f);
    float ye = (float)i * inv511;

    if (tid < 32) idimt[tid] = 1.f / powf(10000.f, (float)(2 * (tid >> 1)) / 32.f);
    if (tid < 192) w1[tid] = wcf1[tid];
    if (tid < 64) b1[tid] = bcf1[tid];
    if (tid < 192) { int r = tid / 64, c = tid - (tid / 64) * 64; wb[tid] = Wc[r * 128 + 64 + c]; }
    if (tid < 3) bcs[tid] = bc[tid];
    __syncthreads();
    if (tid >= 32 && tid < 48) {
        int c = tid - 32;
        float e = ye * idimt[c];
        posy[c] = ((c & 1) == 0) ? __sinf(e) : __cosf(e);
    }

    int ky = i >> 2, ry = i & 3;
    int ym = (ky > 0) ? ky - 1 : 0, yp = (ky < 127) ? ky + 1 : 127;
    float wy0 = (ry == 0) ? .375f : (ry == 1) ? .1875f : (ry == 2) ? .0625f : 0.f;
    float wy1 = (ry == 0 || ry == 3) ? .625f : .75f;
    float wy2 = (ry == 0) ? 0.f : (ry == 1) ? .0625f : (ry == 2) ? .1875f : .375f;
    int base = j0 >> 2;
    int r0 = ym * 128, r1 = ky * 128, r2 = yp * 128;
    for (int idx = tid; idx < 64 * 66; idx += 256) {
        int c = idx / 66, t = idx - c * 66;
        int col = base - 1 + t;
        col = (col < 0) ? 0 : (col > 127) ? 127 : col;
        const float* gp = g4s + (size_t)c * 16384;
        gyr[c][t] = wy0 * gp[r0 + col] + wy1 * gp[r1 + col] + wy2 * gp[r2 + col];
    }
    for (int idx = tid; idx < 3 * 66; idx += 256) {
        int c = idx / 66, t = idx - c * 66;
        int col = base - 1 + t;
        col = (col < 0) ? 0 : (col > 127) ? 127 : col;
        const float* hp = h3s + (size_t)c * 16384;
        hyr[c][t] = wy0 * hp[r0 + col] + wy1 * hp[r1 + col] + wy2 * hp[r2 + col];
    }
    __syncthreads();

    float xe = (float)j * inv511;
    float gm = __int_as_float(gmax[0]);
    float ze = dark[p] / (gm + 1e-6f) * scale;
    float x0 = x[p], x1 = x[p + NPIX], x2 = x[p + 2 * NPIX];

    int rx = j & 3;
    int tx = tid >> 2;
    float wx0 = (rx == 0) ? .375f : (rx == 1) ? .1875f : (rx == 2) ? .0625f : 0.f;
    float wx1 = (rx == 0 || rx == 3) ? .625f : .75f;
    float wx2 = (rx == 0) ? 0.f : (rx == 1) ? .0625f : (rx == 2) ? .1875f : .375f;

    float a0 = 0.f, a1 = 0.f, a2 = 0.f;
    #pragma unroll 1
    for (int c = 0; c < 64; c++) {
        float pos;
        if (c < 16)      { float e = xe * idimt[c];      pos = ((c & 1) == 0) ? __sinf(e) : __cosf(e); }
        else if (c < 32) { pos = posy[c - 16]; }
        else             { float e = ze * idimt[c - 32]; pos = ((c & 1) == 0) ? __sinf(e) : __cosf(e); }
        float ape = pos + w1[c * 3] * x0 + w1[c * 3 + 1] * x1 + w1[c * 3 + 2] * x2 + b1[c];
        float gv = wx0 * gyr[c][tx] + wx1 * gyr[c][tx + 1] + wx2 * gyr[c][tx + 2];
        float s = gv * ape;
        a0 += wb[c] * s; a1 += wb[64 + c] * s; a2 += wb[128 + c] * s;
    }
    float f0 = wx0 * hyr[0][tx] + wx1 * hyr[0][tx + 1] + wx2 * hyr[0][tx + 2];
    float f1 = wx0 * hyr[1][tx] + wx1 * hyr[1][tx + 1] + wx2 * hyr[1][tx + 2];
    float f2 = wx0 * hyr[2][tx] + wx1 * hyr[2][tx + 1] + wx2 * hyr[2][tx + 2];
    out[p]            = a0 + f0 + bcs[0] + x0;
    out[NPIX + p]     = a1 + f1 + bcs[1] + x1;
    out[2 * NPIX + p] = a2 + f2 + bcs[2] + x2;
}

// ================================================================ launcher
extern "C" void kernel_launch(void* const* d_in, const int* in_sizes, int n_in,
                              void* d_out, int out_size, void* d_ws, size_t ws_size,
                              hipStream_t stream) {
    const float* x      = (const float*)d_in[0];
    const float* w_cf1  = (const float*)d_in[1];  const float* b_cf1 = (const float*)d_in[2];
    const float* w_e1   = (const float*)d_in[3];  const float* b_e1  = (const float*)d_in[4];
    const float* w_e2   = (const float*)d_in[5];  const float* b_e2  = (const float*)d_in[6];
    const float* w_d1   = (const float*)d_in[7];  const float* b_d1  = (const float*)d_in[8];
    const float* w_d2   = (const float*)d_in[9];  const float* b_d2  = (const float*)d_in[10];
    // 11..14: pha branch is dead code in the reference
    const float* w_amp1 = (const float*)d_in[15]; const float* b_amp1 = (const float*)d_in[16];
    const float* w_amp2 = (const float*)d_in[17]; const float* b_amp2 = (const float*)d_in[18];
    const float* w_sp1  = (const float*)d_in[19]; const float* b_sp1  = (const float*)d_in[20];
    const float* w_sp2  = (const float*)d_in[21]; const float* b_sp2  = (const float*)d_in[22];
    const float* w_u1   = (const float*)d_in[23]; const float* b_u1   = (const float*)d_in[24];
    const float* w_u2   = (const float*)d_in[25]; const float* b_u2   = (const float*)d_in[26];
    const float* w_u3   = (const float*)d_in[27]; const float* b_u3   = (const float*)d_in[28];
    const float* w_u4   = (const float*)d_in[29]; const float* b_u4   = (const float*)d_in[30];
    const float* w_cf2  = (const float*)d_in[31]; const float* b_cf2  = (const float*)d_in[32];
    const float* w_cf3  = (const float*)d_in[33]; const float* b_cf3  = (const float*)d_in[34];
    float* out = (float*)d_out;

    char* ws = (char*)d_ws;
    constexpr size_t MiB = 1ull << 20;
    float*  dark   = (float*)(ws + 0 * MiB);
    int*    gmax   = (int*)  (ws + 2 * MiB);
    float*  Wc     = (float*)(ws + 2 * MiB + 1024);
    float*  bc     = (float*)(ws + 2 * MiB + 2560);
    float*  W21c   = (float*)(ws + 2 * MiB + 4096);
    float*  b21c   = (float*)(ws + 2 * MiB + 7168);
    unsigned short* d1ch = (unsigned short*)(ws + 3 * MiB);       // bf16 [128][32]
    float*  b1c    = (float*)(ws + 3 * MiB + 16384);
    float*  Uf     = (float*)(ws + 3 * MiB + 32768);              // fp32 [64][256]
    unsigned short* Wg = (unsigned short*)(ws + 3 * MiB + 131072);// bf16 [64][256]
    float*  bgc    = (float*)(ws + 3 * MiB + 196608);
    unsigned short* xd1 = (unsigned short*)(ws + 67 * MiB);   // bf16 [128][65536] = 16 MiB
    unsigned short* xd2 = (unsigned short*)(ws + 99 * MiB);   // bf16 [256][16384] =  8 MiB
    unsigned short* F1T = (unsigned short*)(ws + 115 * MiB);  // bf16 [32768][256] = 16 MiB
    float*  F2C    = (float*)(ws + 147 * MiB);                // fp32 (feeds sqrt fused in amp1)
    float*  A1     = (float*)(ws + 173 * MiB);
    float*  A2     = (float*)(ws + 182 * MiB);
    unsigned short* Zbuf = (unsigned short*)(ws + 115 * MiB); // bf16 (F1T dead after F2)
    unsigned short* I1T  = (unsigned short*)(ws + 132 * MiB); // bf16 [16640][256] = 8.5 MiB
    float*  P      = (float*)(ws + 149 * MiB);                // fp32 [3][65][256] = 200 KB
    float*  h3s    = (float*)(ws + 11 * MiB);                 // fp32 [3][16384]
    unsigned short* s1 = (unsigned short*)(ws + 31 * MiB);    // bf16 [256][16384] = 8 MiB
    float*  g4s    = (float*)(ws + 87 * MiB);                 // fp32 [64][16384]
    unsigned short* wb16 = (unsigned short*)(ws + 192 * MiB);
    unsigned short* d2h = wb16 + 65536,   * d2l = wb16 + 196608;
    unsigned short* a1h = wb16 + 327680,  * a1l = wb16 + 393216;
    unsigned short* a2h = wb16 + 458752,  * a2l = wb16 + 524288;
    unsigned short* s1h = wb16 + 589824;
    unsigned short* BfH = wb16 + 786432,  * BfL = wb16 + 819200;
    unsigned short* BfcH = wb16 + 851968, * BfcL = wb16 + 917504;
    unsigned short* BicH = wb16 + 983040, * BicL = wb16 + 1048576;
    float* zbias = (float*)(ws + 195 * MiB + 512 * 1024);
    float* Birf  = (float*)(ws + 196 * MiB);                  // fp32 [160][128] = 80 KB

    // 1) prepA (also zeroes gmax) ; fused dark channel ; prepB (incl. Wg/bgc)
    k_prepA<<<2064, 256, 0, stream>>>(w_d2, d2h, d2l, w_amp1, a1h, a1l, w_amp2, a2h, a2l, w_sp1, s1h,
                                      w_u3, w_u4, Uf,
                                      BfH, BfL, BfcH, BfcL, BicH, BicL, Birf, zbias, gmax);
    k_dark<<<512, 256, 0, stream>>>(x, dark, gmax);
    k_prepB<<<82, 256, 0, stream>>>(Uf,
                                    w_e1, b_e1, w_e2, b_e2, w_d1, b_d1, d1ch, b1c,
                                    w_u4, b_u3, b_u4, w_sp2, b_sp2, Wg, bgc,
                                    w_cf2, b_cf2, w_cf3, b_cf3, w_u2, b_u2, w_u1, b_u1,
                                    Wc, bc, W21c, b21c);

    // 2) composed d1 = (w_d1∘w_e2∘w_e1) on 2x2 x-patches, K=12→32 ; d2
    k_mmcf<2, 0, 0, 0, 0, 1><<<1024, 256, 0, stream>>>(x, d1ch, nullptr, b1c, xd1, 65536, 128, 32, 0, 0, 0, 2);
    k_mmcf<1, 0, 0, 0, 1, 1><<<512, 256, 0, stream>>>(xd1, d2h, nullptr, b_d2, xd2, 16384, 256, 512, 7, 7, 256, 4);

    // 3) FFT section (amp = sqrt fused into amp1 A-stage)
    k_mmcf<3, 0, 0, 1, 1, 1><<<1024, 256, 0, stream>>>(xd2, BfH, nullptr, zbias, F1T, 32768, 256, 128, 0, 0, 0, 4);
    k_mmcf<7, 0, 0, 0, 1, 0><<<520, 256, 0, stream>>>(F1T, BfcH, nullptr, zbias, F2C, 16640, 256, 256, 0, 0, 0, 4);
    k_mmcf<9, 1, 1, 0, 0, 0><<<260, 256, 0, stream>>>(F2C, a1h, a1l, b_amp1, A1, 8320, 256, 256, 0, 0, 0, 4);
    k_mmcf<0, 1, 0, 0, 0, 0><<<260, 256, 0, stream>>>(A1, a2h, a2l, b_amp2, A2, 8320, 256, 256, 0, 0, 0, 4);
    k_zbuild<<<8320, 256, 0, stream>>>(A2, Zbuf);
    k_mmcf<0, 0, 0, 1, 1, 1><<<520, 256, 0, stream>>>(Zbuf, BicH, nullptr, zbias, I1T, 16640, 256, 256, 0, 0, 0, 4);

    // 4) four path: factored h3 (I2 GEMM algebraically removed):
    //    P = W21c ∘ I1T (contract c) ; h3s = Birf ∘ P (contract k) + b21c
    k_pfold<<<65, 256, 0, stream>>>(I1T, W21c, P);
    k_h3f<<<128, 128, 0, stream>>>(P, Birf, b21c, h3s);

    // 5) spat path: sp1 ; composed (u4·u3·sp2) GEMM (@128^2; upsample folded into k_final)
    k_mmcf<0, 0, 1, 0, 1, 1><<<512, 256, 0, stream>>>(xd2, s1h, nullptr, b_sp1, s1, 16384, 256, 256, 0, 0, 0, 4);
    k_mmcf<0, 0, 0, 0, 1, 0><<<128, 256, 0, stream>>>(s1, Wg, nullptr, bgc, g4s, 16384, 64, 256, 0, 0, 0, 1);

    // 6) final fused stage (y-interp staged in LDS)
    k_final<<<1024, 256, 0, stream>>>(x, dark, gmax, w_cf1, b_cf1, Wc, bc, g4s, h3s, out);
}

// Round 9
// 314.405 us; speedup vs baseline: 1.2407x; 1.0974x over previous
//
#include <hip/hip_runtime.h>
#include <math.h>

#define PI_F 3.14159265358979323846f
#define NPIX 262144   // 512*512

typedef __attribute__((ext_vector_type(8))) short sh8;
typedef __attribute__((ext_vector_type(4))) float fx4;
typedef __attribute__((ext_vector_type(4))) unsigned short ush4;

__device__ __forceinline__ unsigned short f2bf(float v) {
    unsigned u = __float_as_uint(v);
    return (unsigned short)((u + 0x7FFFu + ((u >> 16) & 1)) >> 16);
}
__device__ __forceinline__ float bf2f(unsigned short h) {
    return __uint_as_float((unsigned)h << 16);
}

__device__ __forceinline__ int refl512(int t) {
    if (t < 0) t = -t;
    if (t > 511) t = 1022 - t;
    return t;
}

// ---------------------------------------------------------------- prep helpers (device)
__device__ __forceinline__ void prep_one(const float* __restrict__ w, unsigned short* __restrict__ h,
                                         unsigned short* __restrict__ l, int N, int K, int cshift, int idx) {
    if (idx >= N * K) return;
    int n = idx / K, kord = idx - n * K;
    int ksrc = kord;
    if (cshift) {
        int dydx = kord >> cshift, c = kord & ((1 << cshift) - 1);
        ksrc = c * 4 + dydx;
    }
    float v = w[n * K + ksrc];
    unsigned short hb = f2bf(v);
    h[idx] = hb;
    if (l) l[idx] = f2bf(v - bf2f(hb));
}

// ---------------------------------------------------------------- MEGA prep: weights + DFT tables + composes + dark channel
// block map:
//   [0,512)    d2 weights      [512,768) a1   [768,1024) a2   [1024,1280) s1
//   [1280,2000) DFT tables (Bf/Bfc/Bic/Birf) + zbias
//   [2000,2016) d1ch compose   2016 b1c   2017 Wc/W21c chain
//   [2018,2082) Wg/bgc (Uf row computed inline)
//   [2082,2594) dark channel (writes dark[] + blockmax[i]; separable 15x15 min)
__global__ __launch_bounds__(256) void k_prep(
    const float* __restrict__ x, float* __restrict__ dark, float* __restrict__ blockmax,
    const float* __restrict__ w_d2, unsigned short* __restrict__ d2h, unsigned short* __restrict__ d2l,
    const float* __restrict__ w_a1, unsigned short* __restrict__ a1h, unsigned short* __restrict__ a1l,
    const float* __restrict__ w_a2, unsigned short* __restrict__ a2h, unsigned short* __restrict__ a2l,
    const float* __restrict__ w_s1, unsigned short* __restrict__ s1h,
    unsigned short* __restrict__ BfH, unsigned short* __restrict__ BfL,
    unsigned short* __restrict__ BfcH, unsigned short* __restrict__ BfcL,
    unsigned short* __restrict__ BicH, unsigned short* __restrict__ BicL,
    float* __restrict__ Birf, float* __restrict__ zbias,
    const float* __restrict__ w_e1, const float* __restrict__ b_e1,
    const float* __restrict__ w_e2, const float* __restrict__ b_e2,
    const float* __restrict__ w_d1, const float* __restrict__ b_d1,
    unsigned short* __restrict__ d1ch, float* __restrict__ b1c,
    const float* __restrict__ w_u3, const float* __restrict__ w_u4,
    const float* __restrict__ b_u3, const float* __restrict__ b_u4,
    const float* __restrict__ wsp2, const float* __restrict__ bsp2,
    unsigned short* __restrict__ Wg, float* __restrict__ bgc,
    const float* __restrict__ w2, const float* __restrict__ b2,
    const float* __restrict__ w3, const float* __restrict__ b3,
    const float* __restrict__ wu2, const float* __restrict__ bu2,
    const float* __restrict__ wu1, const float* __restrict__ bu1,
    float* __restrict__ Wc, float* __restrict__ bc,
    float* __restrict__ W21c, float* __restrict__ b21c) {
    __shared__ float smem[8448];   // rm[7680] | cm[512] | red[256] (branch-aliased)
    int b = blockIdx.x, tid = threadIdx.x;
    if (b < 512)       { prep_one(w_d2, d2h, d2l, 256, 512, 7, b * 256 + tid); return; }
    else if (b < 768)  { prep_one(w_a1, a1h, a1l, 256, 256, 0, (b - 512) * 256 + tid); return; }
    else if (b < 1024) { prep_one(w_a2, a2h, a2l, 256, 256, 0, (b - 768) * 256 + tid); return; }
    else if (b < 1280) { prep_one(w_s1, s1h, nullptr, 256, 256, 0, (b - 1024) * 256 + tid); return; }
    else if (b < 2000) {
        int idx = (b - 1280) * 256 + tid;
        if (idx < 256) zbias[idx] = 0.f;
        const float w0 = 2.f * PI_F / 128.f;
        float v;
        unsigned short *H, *L;
        int off;
        if (idx < 32768) {                     // Bf [256][128]
            int n = idx >> 7, k = idx & 127;
            int t = n & 127, r = (t * k) & 127;
            float s_, c_; sincosf(w0 * r, &s_, &c_);
            v = (n < 128) ? c_ : -s_;
            H = BfH; L = BfL; off = idx;
        } else if (idx < 98304) {              // Bfc [256][256]
            int i = idx - 32768;
            int n = i >> 8, j = i & 255;
            int t = n & 127, r = (t * (j & 127)) & 127;
            float s_, c_; sincosf(w0 * r, &s_, &c_);
            v = (n < 128) ? ((j < 128) ? c_ : s_) : ((j < 128) ? -s_ : c_);
            H = BfcH; L = BfcL; off = i;
        } else if (idx < 163840) {             // Bic [256][256]
            int i = idx - 98304;
            int n = i >> 8, j = i & 255;
            int t = n & 127, r = (t * (j & 127)) & 127;
            float s_, c_; sincosf(w0 * r, &s_, &c_);
            v = ((n < 128) ? ((j < 128) ? c_ : -s_) : ((j < 128) ? s_ : c_)) * (1.f / 128.f);
            H = BicH; L = BicL; off = i;
        } else if (idx < 184320) {             // Birf [160][128] fp32
            int i2 = idx - 163840;
            int col = i2 / 160, j = i2 - col * 160;
            if (j == 0) v = 1.f / 128.f;
            else if (j < 64)  { int r = (j * col) & 127; float s_, c_; sincosf(w0 * r, &s_, &c_); v = 2.f * c_ / 128.f; }
            else if (j == 64) v = (col & 1) ? -1.f / 128.f : 1.f / 128.f;
            else if (j >= 66 && j <= 128) { int k = j - 65; int r = (k * col) & 127; float s_, c_; sincosf(w0 * r, &s_, &c_); v = -2.f * s_ / 128.f; }
            else v = 0.f;
            Birf[j * 128 + col] = v;
            return;
        } else return;
        unsigned short hb = f2bf(v);
        H[off] = hb;
        L[off] = f2bf(v - bf2f(hb));
    }
    else if (b < 2016) {                       // d1ch compose
        float* E = smem;                       // [192]
        if (tid < 192) {
            int o = tid / 3, ci = tid - o * 3;
            float s = 0.f;
            #pragma unroll
            for (int r = 0; r < 8; r++) s += w_e2[o * 8 + r] * w_e1[r * 3 + ci];
            E[tid] = s;
        }
        __syncthreads();
        int idx = (b - 2000) * 256 + tid;      // < 4096
        int n = idx >> 5, k = idx & 31;
        float s = 0.f;
        if (k < 12) {
            int dydx = k / 3, ci = k - dydx * 3;
            #pragma unroll 16
            for (int o = 0; o < 64; o++) s += w_d1[n * 256 + o * 4 + dydx] * E[o * 3 + ci];
        }
        d1ch[idx] = f2bf(s);
    } else if (b == 2016) {                    // b1c fold
        float* f = smem;                       // [64]
        if (tid < 64) {
            int o = tid;
            float s = b_e2[o];
            #pragma unroll
            for (int r = 0; r < 8; r++) s += w_e2[o * 8 + r] * b_e1[r];
            f[o] = s;
        }
        __syncthreads();
        if (tid < 128) {
            float s = b_d1[tid];
            #pragma unroll 8
            for (int o = 0; o < 64; o++) {
                float fo = f[o];
                #pragma unroll
                for (int dydx = 0; dydx < 4; dydx++) s += w_d1[tid * 256 + o * 4 + dydx] * fo;
            }
            b1c[tid] = s;
        }
    } else if (b == 2017) {                    // Wc / W21c chain
        float* sWc = smem;                     // [384]
        float* sW2c = smem + 384;              // [384]
        if (tid < 128) {
            int j = tid;
            for (int r = 0; r < 3; r++) {
                float s = 0.f;
                #pragma unroll 16
                for (int o = 0; o < 64; o++) s += w3[r * 64 + o] * w2[o * 128 + j];
                sWc[r * 128 + j] = s;
                Wc[r * 128 + j] = s;
            }
            if (j < 3) {
                float s = b3[j];
                #pragma unroll 16
                for (int o = 0; o < 64; o++) s += w3[j * 64 + o] * b2[o];
                bc[j] = s;
            }
        }
        __syncthreads();
        if (tid < 128) {
            int j = tid;
            for (int r = 0; r < 3; r++) {
                float s = 0.f;
                #pragma unroll 16
                for (int o = 0; o < 64; o++) s += sWc[r * 128 + o] * wu2[o * 128 + j];
                sW2c[r * 128 + j] = s;
            }
        }
        __syncthreads();
        if (tid < 256) {
            int j = tid;
            for (int r = 0; r < 3; r++) {
                float s = 0.f;
                #pragma unroll 16
                for (int o = 0; o < 128; o++) s += sW2c[r * 128 + o] * wu1[o * 256 + j];
                W21c[r * 256 + j] = s;
            }
        }
        if (tid < 3) {
            float s = 0.f;
            #pragma unroll 16
            for (int o = 0; o < 128; o++) s += sW2c[tid * 128 + o] * bu1[o];
            #pragma unroll 16
            for (int o = 0; o < 64; o++)  s += sWc[tid * 128 + o] * bu2[o];
            b21c[tid] = s;
        }
    } else if (b < 2082) {                     // Wg / bgc (Uf row inline)
        int n = b - 2018;
        float* u = smem;                       // [256]
        float* red = smem + 256;               // [256]
        {
            float s = 0.f;
            #pragma unroll 16
            for (int o = 0; o < 128; o++) s += w_u4[n * 128 + o] * w_u3[o * 256 + tid];
            u[tid] = s;
        }
        __syncthreads();
        float s = 0.f;
        #pragma unroll 16
        for (int o = 0; o < 256; o++) s += u[o] * wsp2[o * 256 + tid];
        Wg[n * 256 + tid] = f2bf(s);
        float rv = u[tid] * bsp2[tid];
        if (tid < 128) rv += w_u4[n * 128 + tid] * b_u3[tid];
        red[tid] = rv;
        __syncthreads();
        for (int st = 128; st > 0; st >>= 1) {
            if (tid < st) red[tid] += red[tid + st];
            __syncthreads();
        }
        if (tid == 0) bgc[n] = b_u4[n] + red[0];
    } else {                                   // dark channel, i = b - 2082
        int i = b - 2082;
        float* rm = smem;                      // [15*512]
        float* cm = smem + 7680;               // [512]
        float* red = smem + 8192;              // [256]
        for (int idx = tid; idx < 15 * 512; idx += 256) {
            int rr = idx >> 9, j = idx & 511;
            int row = refl512(i - 7 + rr);
            int p = (row << 9) + j;
            rm[rr * 512 + j] = 1.0f - fmaxf(x[p], fmaxf(x[p + NPIX], x[p + 2 * NPIX]));
        }
        __syncthreads();
        #pragma unroll
        for (int h = 0; h < 2; h++) {
            int j = tid + h * 256;
            float m = 1e30f;
            #pragma unroll
            for (int rr = 0; rr < 15; rr++) m = fminf(m, rm[rr * 512 + j]);
            cm[j] = m;
        }
        __syncthreads();
        float best = -1e30f;
        #pragma unroll
        for (int h = 0; h < 2; h++) {
            int j = tid + h * 256;
            float m = 1e30f;
            #pragma unroll
            for (int d = -7; d <= 7; d++) m = fminf(m, cm[refl512(j + d)]);
            dark[(i << 9) + j] = m;
            best = fmaxf(best, m);
        }
        red[tid] = best;
        __syncthreads();
        for (int s = 128; s > 0; s >>= 1) {
            if (tid < s) red[tid] = fmaxf(red[tid], red[tid + s]);
            __syncthreads();
        }
        if (tid == 0) blockmax[i] = red[0];
    }
}

// ---------------------------------------------------------------- channels-first MFMA GEMM body (LDS passed in)
// non-SPLIT LDS: 7680 shorts ; SPLIT: 15360 shorts
template<int AMODE, int SPLIT, int LRELU, int TSTORE, int ABF16, int CBF16>
__device__ __forceinline__ void mm_body(unsigned short* __restrict__ SH,
                                        const void* __restrict__ Asrc_,
                                        const unsigned short* __restrict__ Bh,
                                        const unsigned short* __restrict__ Bl,
                                        const float* __restrict__ bias, void* __restrict__ C_,
                                        int M, int N, int K, int cshift, int wshift, int srcW,
                                        int gy, int bid, int nwg) {
    const float* Af = (const float*)Asrc_;
    const unsigned short* A16 = (const unsigned short*)Asrc_;
    float* Cf = (float*)C_;
    unsigned short* C16 = (unsigned short*)C_;
    unsigned short* AhS = SH;                  // 128*40
    unsigned short* BhS = SH + 5120;           // 64*40
    unsigned short* AlS = SPLIT ? SH + 7680 : SH;
    unsigned short* BlS = SPLIT ? SH + 12800 : SH;
    int tid = threadIdx.x;
    int qq = nwg >> 3, rr = nwg & 7;
    int xcd = bid & 7, ixw = bid >> 3;
    int work = (xcd < rr) ? (xcd * (qq + 1) + ixw) : (rr * (qq + 1) + (xcd - rr) * qq + ixw);
    int bx = work / gy;
    int by = work - bx * gy;
    int m0 = bx * 128;
    int n0 = by * 64;
    int wave = tid >> 6, lane = tid & 63;
    int wm = (wave >> 1) * 64, wn = (wave & 1) * 32;
    int l15 = lane & 15, quad = lane >> 4;
    int lk = quad * 8, lk4 = quad * 4;
    fx4 acc[4][2];
    #pragma unroll
    for (int a = 0; a < 4; a++)
        #pragma unroll
        for (int b = 0; b < 2; b++)
            acc[a][b] = (fx4){0.f, 0.f, 0.f, 0.f};

    int mm = tid & 127;
    int kpb = tid >> 7;
    int gm = m0 + mm;
    int oj = 0, oi = 0, cA = 0, kfA = 0;
    size_t abase = 0;
    if (AMODE == 1) { oj = gm & ((1 << wshift) - 1); oi = gm >> wshift; }
    if (AMODE == 2) { oj = gm & 255; oi = gm >> 8; }
    if (AMODE == 3) abase = (size_t)gm * K;
    if (AMODE == 7) { cA = gm / 65; kfA = gm - cA * 65; }
    if (AMODE == 9) { cA = gm / 65; kfA = gm - cA * 65; }

    for (int kb = 0; kb < K; kb += 32) {
        if (AMODE == 3 && ABF16 && !SPLIT) {
            #pragma unroll
            for (int half = 0; half < 2; half++) {
                sh8 hv = *(const sh8*)(const void*)&A16[abase + kb + kpb * 16 + half * 8];
                *(sh8*)(void*)&AhS[mm * 40 + (kpb * 2 + half) * 8] = hv;
            }
        } else {
            #pragma unroll
            for (int half = 0; half < 2; half++) {
                sh8 hv, lv;
                #pragma unroll
                for (int tt = 0; tt < 4; tt++) {
                    int kp = kpb * 8 + half * 4 + tt;
                    int k0 = kb + kp * 2;
                    unsigned short h0, h1;
                    if (ABF16) {
                        size_t ad0, ad1;
                        if (AMODE == 0) {
                            ad0 = (size_t)k0 * M + gm;
                            ad1 = ad0 + M;
                        } else if (AMODE == 1) {
                            int c = k0 & ((1 << cshift) - 1);
                            int dydx = k0 >> cshift;
                            int dy = dydx >> 1, dx = dydx & 1;
                            size_t pix = (size_t)(2 * oi + dy) * srcW + (2 * oj + dx);
                            size_t plane = (size_t)srcW * srcW;
                            ad0 = (size_t)c * plane + pix;
                            ad1 = ad0 + plane;
                        } else if (AMODE == 3) {
                            ad0 = abase + k0;
                            ad1 = ad0 + 1;
                        } else {               // AMODE 7
                            int t0 = k0 & 127, hf = k0 >> 7;
                            ad0 = (size_t)(cA * 128 + t0) * 256 + hf * 128 + kfA;
                            ad1 = ad0 + 256;
                        }
                        h0 = A16[ad0];
                        h1 = A16[ad1];
                    } else {
                        float a0, a1;
                        if (AMODE == 2) {
                            if (k0 < 12) {
                                int d0 = k0 / 3, c0 = k0 - d0 * 3;
                                int k1 = k0 + 1;
                                int d1x = k1 / 3, c1 = k1 - d1x * 3;
                                a0 = Af[(size_t)c0 * NPIX + (size_t)(2 * oi + (d0 >> 1)) * 512 + 2 * oj + (d0 & 1)];
                                a1 = Af[(size_t)c1 * NPIX + (size_t)(2 * oi + (d1x >> 1)) * 512 + 2 * oj + (d1x & 1)];
                            } else { a0 = 0.f; a1 = 0.f; }
                        } else if (AMODE == 9) {
                            size_t ad = (size_t)cA * 16640 + (size_t)k0 * 65 + kfA;
                            float re0 = Af[ad], im0 = Af[ad + 2129920];
                            float re1 = Af[ad + 65], im1 = Af[ad + 65 + 2129920];
                            a0 = sqrtf(re0 * re0 + im0 * im0);
                            a1 = sqrtf(re1 * re1 + im1 * im1);
                        } else {
                            size_t ad0 = (size_t)k0 * M + gm;
                            a0 = Af[ad0];
                            a1 = Af[ad0 + M];
                        }
                        h0 = f2bf(a0);
                        h1 = f2bf(a1);
                        if (SPLIT) {
                            lv[tt * 2] = (short)f2bf(a0 - bf2f(h0));
                            lv[tt * 2 + 1] = (short)f2bf(a1 - bf2f(h1));
                        }
                    }
                    hv[tt * 2] = (short)h0;
                    hv[tt * 2 + 1] = (short)h1;
                }
                int coff = (kpb * 2 + half) * 8;
                *(sh8*)(void*)&AhS[mm * 40 + coff] = hv;
                if (SPLIT) *(sh8*)(void*)&AlS[mm * 40 + coff] = lv;
            }
        }
        {
            int n = tid >> 2, seg = tid & 3;
            size_t gb = (size_t)(n0 + n) * K + kb + seg * 8;
            *(sh8*)(void*)&BhS[n * 40 + seg * 8] = *(const sh8*)(const void*)&Bh[gb];
            if (SPLIT) *(sh8*)(void*)&BlS[n * 40 + seg * 8] = *(const sh8*)(const void*)&Bl[gb];
        }
        __syncthreads();
        sh8 af[4], bf[2], afl[4], bfl[2];
        #pragma unroll
        for (int mt = 0; mt < 4; mt++) {
            af[mt] = *(const sh8*)(const void*)&AhS[(wm + mt * 16 + l15) * 40 + lk];
            if (SPLIT) afl[mt] = *(const sh8*)(const void*)&AlS[(wm + mt * 16 + l15) * 40 + lk];
        }
        #pragma unroll
        for (int nt = 0; nt < 2; nt++) {
            bf[nt] = *(const sh8*)(const void*)&BhS[(wn + nt * 16 + l15) * 40 + lk];
            if (SPLIT) bfl[nt] = *(const sh8*)(const void*)&BlS[(wn + nt * 16 + l15) * 40 + lk];
        }
        #pragma unroll
        for (int mt = 0; mt < 4; mt++)
            #pragma unroll
            for (int nt = 0; nt < 2; nt++) {
                acc[mt][nt] = __builtin_amdgcn_mfma_f32_16x16x32_bf16(af[mt], bf[nt], acc[mt][nt], 0, 0, 0);
                if (SPLIT) {
                    acc[mt][nt] = __builtin_amdgcn_mfma_f32_16x16x32_bf16(af[mt], bfl[nt], acc[mt][nt], 0, 0, 0);
                    acc[mt][nt] = __builtin_amdgcn_mfma_f32_16x16x32_bf16(afl[mt], bf[nt], acc[mt][nt], 0, 0, 0);
                }
            }
        __syncthreads();
    }
    #pragma unroll
    for (int nt = 0; nt < 2; nt++) {
        int n = n0 + wn + nt * 16 + l15;
        float bs = bias[n];
        #pragma unroll
        for (int mt = 0; mt < 4; mt++) {
            int mbase = m0 + wm + mt * 16 + lk4;
            if (TSTORE) {
                #pragma unroll
                for (int r = 0; r < 4; r++) {
                    float q = acc[mt][nt][r] + bs;
                    if (LRELU) q = (q < 0.f) ? 0.1f * q : q;
                    if (CBF16) C16[(size_t)(mbase + r) * N + n] = f2bf(q);
                    else       Cf[(size_t)(mbase + r) * N + n] = q;
                }
            } else if (CBF16) {
                ush4 v;
                #pragma unroll
                for (int r = 0; r < 4; r++) {
                    float q = acc[mt][nt][r] + bs;
                    if (LRELU) q = (q < 0.f) ? 0.1f * q : q;
                    v[r] = f2bf(q);
                }
                *(ush4*)(void*)&C16[(size_t)n * M + mbase] = v;
            } else {
                float4 v;
                float* vp = (float*)&v;
                #pragma unroll
                for (int r = 0; r < 4; r++) {
                    float q = acc[mt][nt][r] + bs;
                    if (LRELU) q = (q < 0.f) ? 0.1f * q : q;
                    vp[r] = q;
                }
                *(float4*)&Cf[(size_t)n * M + mbase] = v;
            }
        }
    }
}

// single-GEMM wrapper
template<int AMODE, int SPLIT, int LRELU, int TSTORE, int ABF16, int CBF16>
__global__ __launch_bounds__(256) void k_mmcf(const void* __restrict__ Asrc_,
                                              const unsigned short* __restrict__ Bh,
                                              const unsigned short* __restrict__ Bl,
                                              const float* __restrict__ bias, void* __restrict__ C_,
                                              int M, int N, int K, int cshift, int wshift, int srcW,
                                              int gy) {
    __shared__ unsigned short SH[SPLIT ? 15360 : 7680];
    mm_body<AMODE, SPLIT, LRELU, TSTORE, ABF16, CBF16>(SH, Asrc_, Bh, Bl, bias, C_,
                                                       M, N, K, cshift, wshift, srcW, gy,
                                                       (int)blockIdx.x, (int)gridDim.x);
}

// d1 GEMM + 1 extra block reducing blockmax -> gmax
__global__ __launch_bounds__(256) void k_d1(const float* __restrict__ x,
                                            const unsigned short* __restrict__ d1ch,
                                            const float* __restrict__ b1c, unsigned short* __restrict__ xd1,
                                            const float* __restrict__ blockmax, int* __restrict__ gmax) {
    if (blockIdx.x == 1024) {
        __shared__ float red[256];
        int tid = threadIdx.x;
        red[tid] = fmaxf(blockmax[tid], blockmax[tid + 256]);
        __syncthreads();
        for (int s = 128; s > 0; s >>= 1) {
            if (tid < s) red[tid] = fmaxf(red[tid], red[tid + s]);
            __syncthreads();
        }
        if (tid == 0) gmax[0] = __float_as_int(red[0]);
        return;
    }
    __shared__ unsigned short SH[7680];
    mm_body<2, 0, 0, 0, 0, 1>(SH, x, d1ch, nullptr, b1c, xd1, 65536, 128, 32, 0, 0, 0, 2,
                              (int)blockIdx.x, 1024);
}

// F1 (1024 blocks) || sp1 (512 blocks)
__global__ __launch_bounds__(256) void k_dualA(const unsigned short* __restrict__ xd2,
                                               const unsigned short* __restrict__ BfH,
                                               const float* __restrict__ zbias, unsigned short* __restrict__ F1T,
                                               const unsigned short* __restrict__ s1h,
                                               const float* __restrict__ b_sp1, unsigned short* __restrict__ s1) {
    __shared__ unsigned short SH[7680];
    if (blockIdx.x < 1024)
        mm_body<3, 0, 0, 1, 1, 1>(SH, xd2, BfH, nullptr, zbias, F1T, 32768, 256, 128, 0, 0, 0, 4,
                                  (int)blockIdx.x, 1024);
    else
        mm_body<0, 0, 1, 0, 1, 1>(SH, xd2, s1h, nullptr, b_sp1, s1, 16384, 256, 256, 0, 0, 0, 4,
                                  (int)blockIdx.x - 1024, 512);
}

// F2 (520 blocks) || g4s (128 blocks)
__global__ __launch_bounds__(256) void k_dualB(const unsigned short* __restrict__ F1T,
                                               const unsigned short* __restrict__ BfcH,
                                               const float* __restrict__ zbias, float* __restrict__ F2C,
                                               const unsigned short* __restrict__ s1,
                                               const unsigned short* __restrict__ Wg,
                                               const float* __restrict__ bgc, float* __restrict__ g4s) {
    __shared__ unsigned short SH[7680];
    if (blockIdx.x < 520)
        mm_body<7, 0, 0, 0, 1, 0>(SH, F1T, BfcH, nullptr, zbias, F2C, 16640, 256, 256, 0, 0, 0, 4,
                                  (int)blockIdx.x, 520);
    else
        mm_body<0, 0, 0, 0, 1, 0>(SH, s1, Wg, nullptr, bgc, g4s, 16384, 64, 256, 0, 0, 0, 1,
                                  (int)blockIdx.x - 520, 128);
}

// ---------------------------------------------------------------- z = a*(cos a, sin a), flattened full-wave, bf16
__global__ __launch_bounds__(256) void k_zbuild(const float* __restrict__ A2, unsigned short* __restrict__ Z) {
    int idx = blockIdx.x * 256 + threadIdx.x;   // < 2129920
    int ct = idx / 65, kf = idx - ct * 65;
    int c = ct >> 7, t = ct & 127;
    float a = A2[idx];
    float s_, c_;
    sincosf(a, &s_, &c_);
    size_t m = (size_t)c * 65 + kf;
    Z[(size_t)t * 16640 + m] = f2bf(a * c_);
    Z[2129920 + (size_t)t * 16640 + m] = f2bf(a * s_);
}

// ---------------------------------------------------------------- P[r][kf][ht] = sum_c W21c[r][c] * I1T[(c,kf)][ht]
__global__ __launch_bounds__(256) void k_pfold(const unsigned short* __restrict__ I1T,
                                               const float* __restrict__ W21c, float* __restrict__ P) {
    __shared__ float wa[768];
    int kf = blockIdx.x, tid = threadIdx.x;
    for (int t = tid; t < 768; t += 256) wa[t] = W21c[t];
    __syncthreads();
    float a0 = 0.f, a1 = 0.f, a2 = 0.f;
    #pragma unroll 4
    for (int c = 0; c < 256; c++) {
        float v = bf2f(I1T[(size_t)(c * 65 + kf) * 256 + tid]);
        a0 += wa[c] * v;
        a1 += wa[256 + c] * v;
        a2 += wa[512 + c] * v;
    }
    P[(size_t)(0 * 65 + kf) * 256 + tid] = a0;
    P[(size_t)(1 * 65 + kf) * 256 + tid] = a1;
    P[(size_t)(2 * 65 + kf) * 256 + tid] = a2;
}

// ---------------------------------------------------------------- h3s[r][tau][col] = sum_k Birf[k][col] * P[r][kf(k)][hf(k),tau] + b21c[r]
__global__ __launch_bounds__(128) void k_h3f(const float* __restrict__ P, const float* __restrict__ Birf,
                                             const float* __restrict__ b21c, float* __restrict__ h3s) {
    __shared__ float sp[390];
    __shared__ float bs[3];
    int tau = blockIdx.x, col = threadIdx.x;
    for (int t = col; t < 390; t += 128) {
        int r = t / 130, rem = t - r * 130;
        int hf = rem / 65, kf = rem - hf * 65;
        sp[t] = P[(size_t)(r * 65 + kf) * 256 + hf * 128 + tau];
    }
    if (col < 3) bs[col] = b21c[col];
    __syncthreads();
    float f0 = 0.f, f1 = 0.f, f2 = 0.f;
    for (int k0 = 0; k0 < 130; k0++) {
        float w = Birf[k0 * 128 + col];
        int hf = (k0 >= 65) ? 1 : 0;
        int base = hf ? (65 + k0 - 65) : k0;
        f0 += w * sp[base];
        f1 += w * sp[130 + base];
        f2 += w * sp[260 + base];
    }
    size_t q = (size_t)tau * 128 + col;
    h3s[q]         = f0 + bs[0];
    h3s[16384 + q] = f1 + bs[1];
    h3s[32768 + q] = f2 + bs[2];
}

// ---------------------------------------------------------------- final fused stage @512^2 (y-interp staged in LDS)
__global__ __launch_bounds__(256) void k_final(const float* __restrict__ x,
                                               const float* __restrict__ dark, const int* __restrict__ gmax,
                                               const float* __restrict__ wcf1, const float* __restrict__ bcf1,
                                               const float* __restrict__ Wc, const float* __restrict__ bc,
                                               const float* __restrict__ g4s, const float* __restrict__ h3s,
                                               float* __restrict__ out) {
    __shared__ float idimt[32], w1[192], b1[64], wb[192], bcs[3], posy[16];
    __shared__ float gyr[64][68];
    __shared__ float hyr[3][68];
    int tid = threadIdx.x;
    int bid = blockIdx.x;
    int i = bid >> 1;
    int j0 = (bid & 1) << 8;
    int j = j0 + tid;
    int p = (i << 9) + j;

    const float scale = 2.f * PI_F;
    float inv511 = scale / (511.f + 1e-6f);
    float ye = (float)i * inv511;

    if (tid < 32) idimt[tid] = 1.f / powf(10000.f, (float)(2 * (tid >> 1)) / 32.f);
    if (tid < 192) w1[tid] = wcf1[tid];
    if (tid < 64) b1[tid] = bcf1[tid];
    if (tid < 192) { int r = tid / 64, c = tid - (tid / 64) * 64; wb[tid] = Wc[r * 128 + 64 + c]; }
    if (tid < 3) bcs[tid] = bc[tid];
    __syncthreads();
    if (tid >= 32 && tid < 48) {
        int c = tid - 32;
        float e = ye * idimt[c];
        posy[c] = ((c & 1) == 0) ? __sinf(e) : __cosf(e);
    }

    int ky = i >> 2, ry = i & 3;
    int ym = (ky > 0) ? ky - 1 : 0, yp = (ky < 127) ? ky + 1 : 127;
    float wy0 = (ry == 0) ? .375f : (ry == 1) ? .1875f : (ry == 2) ? .0625f : 0.f;
    float wy1 = (ry == 0 || ry == 3) ? .625f : .75f;
    float wy2 = (ry == 0) ? 0.f : (ry == 1) ? .0625f : (ry == 2) ? .1875f : .375f;
    int base = j0 >> 2;
    int r0 = ym * 128, r1 = ky * 128, r2 = yp * 128;
    for (int idx = tid; idx < 64 * 66; idx += 256) {
        int c = idx / 66, t = idx - c * 66;
        int col = base - 1 + t;
        col = (col < 0) ? 0 : (col > 127) ? 127 : col;
        const float* gp = g4s + (size_t)c * 16384;
        gyr[c][t] = wy0 * gp[r0 + col] + wy1 * gp[r1 + col] + wy2 * gp[r2 + col];
    }
    for (int idx = tid; idx < 3 * 66; idx += 256) {
        int c = idx / 66, t = idx - c * 66;
        int col = base - 1 + t;
        col = (col < 0) ? 0 : (col > 127) ? 127 : col;
        const float* hp = h3s + (size_t)c * 16384;
        hyr[c][t] = wy0 * hp[r0 + col] + wy1 * hp[r1 + col] + wy2 * hp[r2 + col];
    }
    __syncthreads();

    float xe = (float)j * inv511;
    float gm = __int_as_float(gmax[0]);
    float ze = dark[p] / (gm + 1e-6f) * scale;
    float x0 = x[p], x1 = x[p + NPIX], x2 = x[p + 2 * NPIX];

    int rx = j & 3;
    int tx = tid >> 2;
    float wx0 = (rx == 0) ? .375f : (rx == 1) ? .1875f : (rx == 2) ? .0625f : 0.f;
    float wx1 = (rx == 0 || rx == 3) ? .625f : .75f;
    float wx2 = (rx == 0) ? 0.f : (rx == 1) ? .0625f : (rx == 2) ? .1875f : .375f;

    float a0 = 0.f, a1 = 0.f, a2 = 0.f;
    #pragma unroll 1
    for (int c = 0; c < 64; c++) {
        float pos;
        if (c < 16)      { float e = xe * idimt[c];      pos = ((c & 1) == 0) ? __sinf(e) : __cosf(e); }
        else if (c < 32) { pos = posy[c - 16]; }
        else             { float e = ze * idimt[c - 32]; pos = ((c & 1) == 0) ? __sinf(e) : __cosf(e); }
        float ape = pos + w1[c * 3] * x0 + w1[c * 3 + 1] * x1 + w1[c * 3 + 2] * x2 + b1[c];
        float gv = wx0 * gyr[c][tx] + wx1 * gyr[c][tx + 1] + wx2 * gyr[c][tx + 2];
        float s = gv * ape;
        a0 += wb[c] * s; a1 += wb[64 + c] * s; a2 += wb[128 + c] * s;
    }
    float f0 = wx0 * hyr[0][tx] + wx1 * hyr[0][tx + 1] + wx2 * hyr[0][tx + 2];
    float f1 = wx0 * hyr[1][tx] + wx1 * hyr[1][tx + 1] + wx2 * hyr[1][tx + 2];
    float f2 = wx0 * hyr[2][tx] + wx1 * hyr[2][tx + 1] + wx2 * hyr[2][tx + 2];
    out[p]            = a0 + f0 + bcs[0] + x0;
    out[NPIX + p]     = a1 + f1 + bcs[1] + x1;
    out[2 * NPIX + p] = a2 + f2 + bcs[2] + x2;
}

// ================================================================ launcher
extern "C" void kernel_launch(void* const* d_in, const int* in_sizes, int n_in,
                              void* d_out, int out_size, void* d_ws, size_t ws_size,
                              hipStream_t stream) {
    const float* x      = (const float*)d_in[0];
    const float* w_cf1  = (const float*)d_in[1];  const float* b_cf1 = (const float*)d_in[2];
    const float* w_e1   = (const float*)d_in[3];  const float* b_e1  = (const float*)d_in[4];
    const float* w_e2   = (const float*)d_in[5];  const float* b_e2  = (const float*)d_in[6];
    const float* w_d1   = (const float*)d_in[7];  const float* b_d1  = (const float*)d_in[8];
    const float* w_d2   = (const float*)d_in[9];  const float* b_d2  = (const float*)d_in[10];
    // 11..14: pha branch is dead code in the reference
    const float* w_amp1 = (const float*)d_in[15]; const float* b_amp1 = (const float*)d_in[16];
    const float* w_amp2 = (const float*)d_in[17]; const float* b_amp2 = (const float*)d_in[18];
    const float* w_sp1  = (const float*)d_in[19]; const float* b_sp1  = (const float*)d_in[20];
    const float* w_sp2  = (const float*)d_in[21]; const float* b_sp2  = (const float*)d_in[22];
    const float* w_u1   = (const float*)d_in[23]; const float* b_u1   = (const float*)d_in[24];
    const float* w_u2   = (const float*)d_in[25]; const float* b_u2   = (const float*)d_in[26];
    const float* w_u3   = (const float*)d_in[27]; const float* b_u3   = (const float*)d_in[28];
    const float* w_u4   = (const float*)d_in[29]; const float* b_u4   = (const float*)d_in[30];
    const float* w_cf2  = (const float*)d_in[31]; const float* b_cf2  = (const float*)d_in[32];
    const float* w_cf3  = (const float*)d_in[33]; const float* b_cf3  = (const float*)d_in[34];
    float* out = (float*)d_out;

    char* ws = (char*)d_ws;
    constexpr size_t MiB = 1ull << 20;
    float*  dark   = (float*)(ws + 0 * MiB);
    int*    gmax   = (int*)  (ws + 2 * MiB);
    float*  Wc     = (float*)(ws + 2 * MiB + 1024);
    float*  bc     = (float*)(ws + 2 * MiB + 2560);
    float*  W21c   = (float*)(ws + 2 * MiB + 4096);
    float*  b21c   = (float*)(ws + 2 * MiB + 7168);
    float*  blockmax = (float*)(ws + 2 * MiB + 8192);             // [512]
    unsigned short* d1ch = (unsigned short*)(ws + 3 * MiB);       // bf16 [128][32]
    float*  b1c    = (float*)(ws + 3 * MiB + 16384);
    unsigned short* Wg = (unsigned short*)(ws + 3 * MiB + 131072);// bf16 [64][256]
    float*  bgc    = (float*)(ws + 3 * MiB + 196608);
    unsigned short* xd1 = (unsigned short*)(ws + 67 * MiB);   // bf16 [128][65536] = 16 MiB
    unsigned short* xd2 = (unsigned short*)(ws + 99 * MiB);   // bf16 [256][16384] =  8 MiB
    unsigned short* F1T = (unsigned short*)(ws + 115 * MiB);  // bf16 [32768][256] = 16 MiB
    float*  F2C    = (float*)(ws + 147 * MiB);                // fp32 (feeds sqrt fused in amp1)
    float*  A1     = (float*)(ws + 173 * MiB);
    float*  A2     = (float*)(ws + 182 * MiB);
    unsigned short* Zbuf = (unsigned short*)(ws + 115 * MiB); // bf16 (F1T dead after F2)
    unsigned short* I1T  = (unsigned short*)(ws + 132 * MiB); // bf16 [16640][256] = 8.5 MiB
    float*  P      = (float*)(ws + 149 * MiB);                // fp32 [3][65][256]
    float*  h3s    = (float*)(ws + 11 * MiB);                 // fp32 [3][16384]
    unsigned short* s1 = (unsigned short*)(ws + 31 * MiB);    // bf16 [256][16384] = 8 MiB
    float*  g4s    = (float*)(ws + 87 * MiB);                 // fp32 [64][16384]
    unsigned short* wb16 = (unsigned short*)(ws + 192 * MiB);
    unsigned short* d2h = wb16 + 65536,   * d2l = wb16 + 196608;
    unsigned short* a1h = wb16 + 327680,  * a1l = wb16 + 393216;
    unsigned short* a2h = wb16 + 458752,  * a2l = wb16 + 524288;
    unsigned short* s1h = wb16 + 589824;
    unsigned short* BfH = wb16 + 786432,  * BfL = wb16 + 819200;
    unsigned short* BfcH = wb16 + 851968, * BfcL = wb16 + 917504;
    unsigned short* BicH = wb16 + 983040, * BicL = wb16 + 1048576;
    float* zbias = (float*)(ws + 195 * MiB + 512 * 1024);
    float* Birf  = (float*)(ws + 196 * MiB);                  // fp32 [160][128]

    // 1) mega prep: weights + tables + composes + dark (2594 blocks, one launch)
    k_prep<<<2594, 256, 0, stream>>>(
        x, dark, blockmax,
        w_d2, d2h, d2l, w_amp1, a1h, a1l, w_amp2, a2h, a2l, w_sp1, s1h,
        BfH, BfL, BfcH, BfcL, BicH, BicL, Birf, zbias,
        w_e1, b_e1, w_e2, b_e2, w_d1, b_d1, d1ch, b1c,
        w_u3, w_u4, b_u3, b_u4, w_sp2, b_sp2, Wg, bgc,
        w_cf2, b_cf2, w_cf3, b_cf3, w_u2, b_u2, w_u1, b_u1,
        Wc, bc, W21c, b21c);

    // 2) d1 (+ gmax reduce rides along) ; d2
    k_d1<<<1025, 256, 0, stream>>>(x, d1ch, b1c, xd1, blockmax, gmax);
    k_mmcf<1, 0, 0, 0, 1, 1><<<512, 256, 0, stream>>>(xd1, d2h, nullptr, b_d2, xd2, 16384, 256, 512, 7, 7, 256, 4);

    // 3) F1 || sp1 ; F2 || g4s  (spat path overlapped with FFT path)
    k_dualA<<<1536, 256, 0, stream>>>(xd2, BfH, zbias, F1T, s1h, b_sp1, s1);
    k_dualB<<<648, 256, 0, stream>>>(F1T, BfcH, zbias, F2C, s1, Wg, bgc, g4s);

    // 4) amp MLP (sqrt fused in amp1 A-stage) ; zbuild ; I1
    k_mmcf<9, 1, 1, 0, 0, 0><<<260, 256, 0, stream>>>(F2C, a1h, a1l, b_amp1, A1, 8320, 256, 256, 0, 0, 0, 4);
    k_mmcf<0, 1, 0, 0, 0, 0><<<260, 256, 0, stream>>>(A1, a2h, a2l, b_amp2, A2, 8320, 256, 256, 0, 0, 0, 4);
    k_zbuild<<<8320, 256, 0, stream>>>(A2, Zbuf);
    k_mmcf<0, 0, 0, 1, 1, 1><<<520, 256, 0, stream>>>(Zbuf, BicH, nullptr, zbias, I1T, 16640, 256, 256, 0, 0, 0, 4);

    // 5) factored h3: P = W21c ∘ I1T ; h3s = Birf ∘ P
    k_pfold<<<65, 256, 0, stream>>>(I1T, W21c, P);
    k_h3f<<<128, 128, 0, stream>>>(P, Birf, b21c, h3s);

    // 6) final fused stage
    k_final<<<1024, 256, 0, stream>>>(x, dark, gmax, w_cf1, b_cf1, Wc, bc, g4s, h3s, out);
}